// Round 1
// baseline (5727.726 us; speedup 1.0000x reference)
//
#include <hip/hip_runtime.h>
#include <math.h>

// ---------------------------------------------------------------------------
// Generic fp32 GEMM: C[M,N] = A[M,K] * B[N,K]^T + bias[N] (+ res[M,N]) (+relu)
// A rows are remapped: row r -> A + (r/rpbA)*bstrideA + (r%rpbA)*ldA
// (lets conv1/conv2 run as GEMMs over contiguous [p..p+2,:] windows).
// Tile 128x128xBK16, 256 threads, 8x8 per thread.
// ---------------------------------------------------------------------------
__global__ __launch_bounds__(256) void gemm_bt_k(
    const float* __restrict__ A, int rpbA, long long bstrideA, int ldA,
    const float* __restrict__ B,
    const float* __restrict__ bias,
    const float* __restrict__ res,
    float* __restrict__ C,
    int M, int N, int K, int relu)
{
    const int BK = 16;
    __shared__ float As[16][132];
    __shared__ float Bs[16][132];
    int t  = threadIdx.x;
    int m0 = blockIdx.y * 128;
    int n0 = blockIdx.x * 128;
    int tm = (t >> 4) << 3;   // 0..120
    int tn = (t & 15) << 3;   // 0..120

    int row1 = t >> 2;        // 0..63
    int kc   = (t & 3) << 2;  // 0,4,8,12
    int r1 = m0 + row1, r2 = m0 + row1 + 64;
    const float* ap1 = (r1 < M) ? A + (long long)(r1 / rpbA) * bstrideA + (long long)(r1 % rpbA) * ldA : nullptr;
    const float* ap2 = (r2 < M) ? A + (long long)(r2 / rpbA) * bstrideA + (long long)(r2 % rpbA) * ldA : nullptr;
    const float* bp1 = B + (long long)(n0 + row1) * K;
    const float* bp2 = B + (long long)(n0 + row1 + 64) * K;

    float acc[8][8] = {};

    for (int k0 = 0; k0 < K; k0 += BK) {
        float4 a1 = ap1 ? *(const float4*)(ap1 + k0 + kc) : make_float4(0.f, 0.f, 0.f, 0.f);
        float4 a2 = ap2 ? *(const float4*)(ap2 + k0 + kc) : make_float4(0.f, 0.f, 0.f, 0.f);
        float4 b1 = *(const float4*)(bp1 + k0 + kc);
        float4 b2 = *(const float4*)(bp2 + k0 + kc);
        As[kc + 0][row1] = a1.x; As[kc + 1][row1] = a1.y; As[kc + 2][row1] = a1.z; As[kc + 3][row1] = a1.w;
        As[kc + 0][row1 + 64] = a2.x; As[kc + 1][row1 + 64] = a2.y; As[kc + 2][row1 + 64] = a2.z; As[kc + 3][row1 + 64] = a2.w;
        Bs[kc + 0][row1] = b1.x; Bs[kc + 1][row1] = b1.y; Bs[kc + 2][row1] = b1.z; Bs[kc + 3][row1] = b1.w;
        Bs[kc + 0][row1 + 64] = b2.x; Bs[kc + 1][row1 + 64] = b2.y; Bs[kc + 2][row1 + 64] = b2.z; Bs[kc + 3][row1 + 64] = b2.w;
        __syncthreads();
        #pragma unroll
        for (int kk = 0; kk < BK; kk++) {
            float a[8], b[8];
            *(float4*)&a[0] = *(const float4*)&As[kk][tm];
            *(float4*)&a[4] = *(const float4*)&As[kk][tm + 4];
            *(float4*)&b[0] = *(const float4*)&Bs[kk][tn];
            *(float4*)&b[4] = *(const float4*)&Bs[kk][tn + 4];
            #pragma unroll
            for (int i = 0; i < 8; i++)
                #pragma unroll
                for (int j = 0; j < 8; j++)
                    acc[i][j] = fmaf(a[i], b[j], acc[i][j]);
        }
        __syncthreads();
    }

    float bi[8];
    *(float4*)&bi[0] = *(const float4*)(bias + n0 + tn);
    *(float4*)&bi[4] = *(const float4*)(bias + n0 + tn + 4);
    for (int i = 0; i < 8; i++) {
        int r = m0 + tm + i;
        if (r >= M) break;
        float o[8];
        #pragma unroll
        for (int j = 0; j < 8; j++) o[j] = acc[i][j] + bi[j];
        if (res) {
            float4 r0 = *(const float4*)(res + (long long)r * N + n0 + tn);
            float4 r4 = *(const float4*)(res + (long long)r * N + n0 + tn + 4);
            o[0] += r0.x; o[1] += r0.y; o[2] += r0.z; o[3] += r0.w;
            o[4] += r4.x; o[5] += r4.y; o[6] += r4.z; o[7] += r4.w;
        }
        if (relu) {
            #pragma unroll
            for (int j = 0; j < 8; j++) o[j] = fmaxf(o[j], 0.f);
        }
        *(float4*)(C + (long long)r * N + n0 + tn)     = make_float4(o[0], o[1], o[2], o[3]);
        *(float4*)(C + (long long)r * N + n0 + tn + 4) = make_float4(o[4], o[5], o[6], o[7]);
    }
}

// ---------------------------------------------------------------------------
// Softsign attention: O[b,s,h*64+d] = sum_t softsign(0.125*q.k) * v
// Block: one (b,h) and 64 s-rows. Streams K/V in 64-chunks through LDS.
// qst/kss stored [d][row] (transposed) so score inner loop does float4 reads.
// Score tile round-trips through LDS reusing the kss buffer.
// ---------------------------------------------------------------------------
__global__ __launch_bounds__(256) void attn_k(
    const float* __restrict__ Q, const float* __restrict__ Kx,
    const float* __restrict__ V, float* __restrict__ O)
{
    __shared__ float qst[64][68];  // [d][s]
    __shared__ float kss[64][68];  // [d][t], later reused as ss[s][t]
    __shared__ float vss[64][68];  // [t][d]
    int t  = threadIdx.x;
    int b  = blockIdx.y >> 4;
    int hh = blockIdx.y & 15;
    int s0 = blockIdx.x << 6;
    long long qbase = ((long long)(b << 10) + s0) << 10;
    int hoff = hh << 6;

    #pragma unroll
    for (int i = 0; i < 4; i++) {
        int f = t + (i << 8);
        int row = f >> 4;
        int c = (f & 15) << 2;
        float4 qv = *(const float4*)(Q + qbase + ((long long)row << 10) + hoff + c);
        qst[c + 0][row] = qv.x; qst[c + 1][row] = qv.y; qst[c + 2][row] = qv.z; qst[c + 3][row] = qv.w;
    }

    int tmr = (t >> 4) << 2;  // s-local base
    int tnr = (t & 15) << 2;  // t-local / d-local base
    float wacc[4][4] = {};

    for (int t0 = 0; t0 < 1024; t0 += 64) {
        long long kbase = ((long long)(b << 10) + t0) << 10;
        #pragma unroll
        for (int i = 0; i < 4; i++) {
            int f = t + (i << 8);
            int row = f >> 4;
            int c = (f & 15) << 2;
            float4 kv = *(const float4*)(Kx + kbase + ((long long)row << 10) + hoff + c);
            kss[c + 0][row] = kv.x; kss[c + 1][row] = kv.y; kss[c + 2][row] = kv.z; kss[c + 3][row] = kv.w;
            float4 vv = *(const float4*)(V + kbase + ((long long)row << 10) + hoff + c);
            *(float4*)&vss[row][c] = vv;
        }
        __syncthreads();

        float sc[4][4] = {};
        #pragma unroll 8
        for (int d = 0; d < 64; d++) {
            float a[4], bb[4];
            *(float4*)a  = *(const float4*)&qst[d][tmr];
            *(float4*)bb = *(const float4*)&kss[d][tnr];
            #pragma unroll
            for (int i = 0; i < 4; i++)
                #pragma unroll
                for (int j = 0; j < 4; j++)
                    sc[i][j] = fmaf(a[i], bb[j], sc[i][j]);
        }
        __syncthreads();

        float (*ss)[68] = kss;
        #pragma unroll
        for (int i = 0; i < 4; i++)
            #pragma unroll
            for (int j = 0; j < 4; j++) {
                float v = sc[i][j] * 0.125f;
                ss[tmr + i][tnr + j] = v / (1.0f + fabsf(v));
            }
        __syncthreads();

        #pragma unroll 8
        for (int tt = 0; tt < 64; tt++) {
            float av[4];
            av[0] = ss[tmr + 0][tt]; av[1] = ss[tmr + 1][tt];
            av[2] = ss[tmr + 2][tt]; av[3] = ss[tmr + 3][tt];
            float vbv[4];
            *(float4*)vbv = *(const float4*)&vss[tt][tnr];
            #pragma unroll
            for (int i = 0; i < 4; i++)
                #pragma unroll
                for (int j = 0; j < 4; j++)
                    wacc[i][j] = fmaf(av[i], vbv[j], wacc[i][j]);
        }
        __syncthreads();
    }

    #pragma unroll
    for (int i = 0; i < 4; i++)
        *(float4*)(O + qbase + ((long long)(tmr + i) << 10) + hoff + tnr) =
            make_float4(wacc[i][0], wacc[i][1], wacc[i][2], wacc[i][3]);
}

// ---------------------------------------------------------------------------
// Torch-style LayerNorm over D=1024: unbiased var (n-1), eps added to STD.
// One block per row, 256 threads x float4.
// ---------------------------------------------------------------------------
__global__ __launch_bounds__(256) void layernorm_k(
    const float* __restrict__ x, const float* __restrict__ w,
    const float* __restrict__ b, float* __restrict__ y)
{
    int row = blockIdx.x;
    int t = threadIdx.x;
    float4 v = ((const float4*)(x + ((long long)row << 10)))[t];
    float s = v.x + v.y + v.z + v.w;
    #pragma unroll
    for (int o = 32; o; o >>= 1) s += __shfl_down(s, o);
    __shared__ float red[4];
    __shared__ float red2[4];
    int wid = t >> 6, lane = t & 63;
    if (lane == 0) red[wid] = s;
    __syncthreads();
    float mean = (red[0] + red[1] + red[2] + red[3]) * (1.0f / 1024.0f);
    float dx = v.x - mean, dy = v.y - mean, dz = v.z - mean, dw = v.w - mean;
    float sq = dx * dx + dy * dy + dz * dz + dw * dw;
    #pragma unroll
    for (int o = 32; o; o >>= 1) sq += __shfl_down(sq, o);
    if (lane == 0) red2[wid] = sq;
    __syncthreads();
    float var = (red2[0] + red2[1] + red2[2] + red2[3]) * (1.0f / 1023.0f);
    float inv = 1.0f / (sqrtf(var) + 1e-6f);
    float4 W  = ((const float4*)w)[t];
    float4 Bv = ((const float4*)b)[t];
    float4 o;
    o.x = W.x * (dx * inv) + Bv.x;
    o.y = W.y * (dy * inv) + Bv.y;
    o.z = W.z * (dz * inv) + Bv.z;
    o.w = W.w * (dw * inv) + Bv.w;
    ((float4*)(y + ((long long)row << 10)))[t] = o;
}

// ---------------------------------------------------------------------------
// Sinusoidal positional encoding add (computed on the fly).
// ---------------------------------------------------------------------------
__global__ __launch_bounds__(256) void add_pos_k(float* __restrict__ h)
{
    int idx = blockIdx.x * 256 + threadIdx.x;   // 0 .. 4194303
    int d = idx & 1023;
    int s = (idx >> 10) & 1023;
    int e = d & ~1;
    float div = expf(-9.210340371976184f * (float)e * (1.0f / 1024.0f));
    float arg = (float)s * div;
    float pe = (d & 1) ? cosf(arg) : sinf(arg);
    h[idx] += pe;
}

// ---------------------------------------------------------------------------
// Conv weight reorder: [OC][IC][3] -> [OC][3][IC]
// ---------------------------------------------------------------------------
__global__ __launch_bounds__(256) void reorder_w_k(
    const float* __restrict__ src, float* __restrict__ dst, int OC, int IC)
{
    int idx = blockIdx.x * 256 + threadIdx.x;
    if (idx >= OC * IC * 3) return;
    int k  = idx % 3;
    int ic = (idx / 3) % IC;
    int oc = idx / (3 * IC);
    dst[(oc * 3 + k) * IC + ic] = src[idx];
}

// ---------------------------------------------------------------------------
// Mean pool over S=1024: pooled[b,d] = mean_s h[b,s,d]
// ---------------------------------------------------------------------------
__global__ __launch_bounds__(256) void meanpool_k(
    const float* __restrict__ h, float* __restrict__ p)
{
    int g = blockIdx.x * 256 + threadIdx.x;  // 0..4095
    int b = g >> 10, d = g & 1023;
    const float* base = h + ((long long)b << 20) + d;
    float s = 0.f;
    for (int i = 0; i < 1024; i++) s += base[(long long)i << 10];
    p[g] = s * (1.0f / 1024.0f);
}

// ---------------------------------------------------------------------------
// Final FC: out[b] = dot(pooled[b,:], fc_w[0,:]) + fc_b[0]
// ---------------------------------------------------------------------------
__global__ __launch_bounds__(256) void fc_k(
    const float* __restrict__ p, const float* __restrict__ w,
    const float* __restrict__ fb, float* __restrict__ out)
{
    int b = blockIdx.x, t = threadIdx.x;
    float s = 0.f;
    for (int i = t; i < 1024; i += 256) s += p[(b << 10) + i] * w[i];
    #pragma unroll
    for (int o = 32; o; o >>= 1) s += __shfl_down(s, o);
    __shared__ float red[4];
    if ((t & 63) == 0) red[t >> 6] = s;
    __syncthreads();
    if (t == 0) out[b] = red[0] + red[1] + red[2] + red[3] + fb[0];
}

// ---------------------------------------------------------------------------
extern "C" void kernel_launch(void* const* d_in, const int* in_sizes, int n_in,
                              void* d_out, int out_size, void* d_ws, size_t ws_size,
                              hipStream_t stream)
{
    const float* x    = (const float*)d_in[0];
    const float* c1w  = (const float*)d_in[1];
    const float* c1b  = (const float*)d_in[2];
    const float* c2w  = (const float*)d_in[3];
    const float* c2b  = (const float*)d_in[4];
    const float* lnAw = (const float*)d_in[5];
    const float* lnAb = (const float*)d_in[6];
    const float* qw   = (const float*)d_in[7];
    const float* qbi  = (const float*)d_in[8];
    const float* kw   = (const float*)d_in[9];
    const float* kbi  = (const float*)d_in[10];
    const float* vw   = (const float*)d_in[11];
    const float* vbi  = (const float*)d_in[12];
    const float* ow   = (const float*)d_in[13];
    const float* obi  = (const float*)d_in[14];
    const float* lnBw = (const float*)d_in[15];
    const float* lnBb = (const float*)d_in[16];
    const float* f1w  = (const float*)d_in[17];
    const float* f1b  = (const float*)d_in[18];
    const float* f2w  = (const float*)d_in[19];
    const float* f2b  = (const float*)d_in[20];
    const float* fcw  = (const float*)d_in[21];
    const float* fcb  = (const float*)d_in[22];
    float* out = (float*)d_out;

    float* ws = (float*)d_ws;
    // workspace layout (floats):
    float* h      = ws;               // 4,194,304
    float* hn     = ws + 4194304;     // 4,194,304 (also wv output of attention)
    float* q_buf  = ws + 8388608;     // 4,194,304 (also h1 during conv, ff low half)
    float* k_buf  = ws + 12582912;    // 4,194,304 (ff high half)
    float* v_buf  = ws + 16777216;    // 4,194,304
    float* w1t    = ws + 20971520;    // 98,304
    float* w2t    = ws + 21069824;    // 1,572,864
    float* pooled = ws + 22642688;    // 4,096     (total ~90.6 MB)
    float* h1 = q_buf;
    float* ff = q_buf;

    // conv weight reorders
    reorder_w_k<<<dim3(384),  dim3(256), 0, stream>>>(c1w, w1t, 512, 64);
    reorder_w_k<<<dim3(6144), dim3(256), 0, stream>>>(c2w, w2t, 1024, 512);

    // conv1 as GEMM: M=4*1026, N=512, K=3*64 (window [p..p+2,:] is contiguous)
    gemm_bt_k<<<dim3(4, 33), 256, 0, stream>>>(
        x, 1026, 1028LL * 64, 64, w1t, c1b, nullptr, h1, 4104, 512, 192, 0);
    // conv2 as GEMM: M=4*1024, N=1024, K=3*512
    gemm_bt_k<<<dim3(8, 32), 256, 0, stream>>>(
        h1, 1024, 1026LL * 512, 512, w2t, c2b, nullptr, h, 4096, 1024, 1536, 0);
    // + positional encoding
    add_pos_k<<<dim3(16384), dim3(256), 0, stream>>>(h);

    for (int l = 0; l < 4; l++) {
        long long wo  = (long long)l * 1048576;  // D*D
        long long wo2 = (long long)l * 2097152;  // 2D*D
        layernorm_k<<<dim3(4096), 256, 0, stream>>>(h, lnAw + l * 1024, lnAb + l * 1024, hn);
        gemm_bt_k<<<dim3(8, 32), 256, 0, stream>>>(
            hn, 4096, 0, 1024, qw + wo, qbi + l * 1024, nullptr, q_buf, 4096, 1024, 1024, 0);
        gemm_bt_k<<<dim3(8, 32), 256, 0, stream>>>(
            hn, 4096, 0, 1024, kw + wo, kbi + l * 1024, nullptr, k_buf, 4096, 1024, 1024, 0);
        gemm_bt_k<<<dim3(8, 32), 256, 0, stream>>>(
            hn, 4096, 0, 1024, vw + wo, vbi + l * 1024, nullptr, v_buf, 4096, 1024, 1024, 0);
        attn_k<<<dim3(16, 64), 256, 0, stream>>>(q_buf, k_buf, v_buf, hn);
        gemm_bt_k<<<dim3(8, 32), 256, 0, stream>>>(
            hn, 4096, 0, 1024, ow + wo, obi + l * 1024, h, h, 4096, 1024, 1024, 0);
        layernorm_k<<<dim3(4096), 256, 0, stream>>>(h, lnBw + l * 1024, lnBb + l * 1024, hn);
        gemm_bt_k<<<dim3(16, 32), 256, 0, stream>>>(
            hn, 4096, 0, 1024, f1w + wo2, f1b + l * 2048, nullptr, ff, 4096, 2048, 1024, 1);
        gemm_bt_k<<<dim3(8, 32), 256, 0, stream>>>(
            ff, 4096, 0, 2048, f2w + wo2, f2b + l * 1024, h, h, 4096, 1024, 2048, 0);
    }

    meanpool_k<<<dim3(16), 256, 0, stream>>>(h, pooled);
    fc_k<<<dim3(4), 256, 0, stream>>>(pooled, fcw, fcb, out);
}

// Round 2
// 2551.049 us; speedup vs baseline: 2.2452x; 2.2452x over previous
//
#include <hip/hip_runtime.h>
#include <hip/hip_bf16.h>
#include <math.h>

// ---------------------------------------------------------------------------
// helpers
// ---------------------------------------------------------------------------
typedef __bf16 v8bf __attribute__((ext_vector_type(8)));
typedef float  v4f  __attribute__((ext_vector_type(4)));

__device__ __forceinline__ unsigned short f2bfu(float f) {
    unsigned u = __builtin_bit_cast(unsigned, f);
    unsigned r = (u + 0x7fffu + ((u >> 16) & 1u)) >> 16;
    return (unsigned short)r;
}
__device__ __forceinline__ float bf2f(unsigned short u) {
    unsigned x = ((unsigned)u) << 16;
    return __builtin_bit_cast(float, x);
}

#define GLDS16(g, s)                                                        \
    __builtin_amdgcn_global_load_lds(                                       \
        (const __attribute__((address_space(1))) void*)(g),                 \
        (__attribute__((address_space(3))) void*)(s), 16, 0, 0)

// ---------------------------------------------------------------------------
// bf16 MFMA GEMM: C[M,N] = A[M,K] * B[N,K]^T + bias (+res fp32) (+relu)
// A row remap: r -> A + (r/rpbA)*bstrideA + (r%rpbA)*ldA   (conv-as-GEMM)
// 128x128 tile, BK=32, 256 thr = 4 waves in 2x2 grid, 4x4 MFMAs/wave.
// LDS is FRAGMENT-CONTIGUOUS: tile As[mtile][lane][8] so that both the
// global_load_lds destination (base + lane*16) and the ds_read_b128
// fragment fetch (base + lane*16) are the same conflict-free pattern.
// ---------------------------------------------------------------------------
__global__ __launch_bounds__(256) void gemm_mfma_k(
    const __hip_bfloat16* __restrict__ A, int rpbA, long long bstrideA, int ldA,
    const __hip_bfloat16* __restrict__ B,
    const float* __restrict__ bias,
    const float* __restrict__ res,
    float* __restrict__ Cf,
    __hip_bfloat16* __restrict__ Cb,
    int M, int N, int K, int relu)
{
    __shared__ __align__(16) __hip_bfloat16 As[8][64][8];
    __shared__ __align__(16) __hip_bfloat16 Bs[8][64][8];
    const int t  = threadIdx.x;
    const int w  = t >> 6;
    const int l  = t & 63;
    const int m0 = blockIdx.y * 128;
    const int n0 = blockIdx.x * 128;
    const int r16 = l & 15;
    const int qb  = l >> 4;          // 0..3 col-block (8 bf16 = 16B)
    const int wm = w >> 1, wn = w & 1;

    // staging source pointers: wave w stages m/n-tiles {2w, 2w+1}
    const __hip_bfloat16* gA[2];
    const __hip_bfloat16* gB[2];
#pragma unroll
    for (int tt = 0; tt < 2; tt++) {
        int arow = m0 + 16 * (2 * w + tt) + r16;
        gA[tt] = A + (long long)(arow / rpbA) * bstrideA
                   + (long long)(arow % rpbA) * ldA + qb * 8;
        int brow = n0 + 16 * (2 * w + tt) + r16;
        gB[tt] = B + (long long)brow * K + qb * 8;
    }

    v4f acc[4][4];
#pragma unroll
    for (int i = 0; i < 4; i++)
#pragma unroll
        for (int j = 0; j < 4; j++) acc[i][j] = (v4f){0.f, 0.f, 0.f, 0.f};

    for (int k0 = 0; k0 < K; k0 += 32) {
        GLDS16(gA[0] + k0, &As[2 * w + 0][0][0]);
        GLDS16(gA[1] + k0, &As[2 * w + 1][0][0]);
        GLDS16(gB[0] + k0, &Bs[2 * w + 0][0][0]);
        GLDS16(gB[1] + k0, &Bs[2 * w + 1][0][0]);
        __syncthreads();
        v8bf af[4], bfr[4];
#pragma unroll
        for (int i = 0; i < 4; i++) af[i]  = *(const v8bf*)(&As[4 * wm + i][l][0]);
#pragma unroll
        for (int j = 0; j < 4; j++) bfr[j] = *(const v8bf*)(&Bs[4 * wn + j][l][0]);
        __syncthreads();
#pragma unroll
        for (int i = 0; i < 4; i++)
#pragma unroll
            for (int j = 0; j < 4; j++)
                acc[i][j] = __builtin_amdgcn_mfma_f32_16x16x32_bf16(
                    af[i], bfr[j], acc[i][j], 0, 0, 0);
    }

    // epilogue: C/D layout col=lane&15, row=(lane>>4)*4+reg
    float bv[4];
#pragma unroll
    for (int j = 0; j < 4; j++) bv[j] = bias[n0 + 64 * wn + 16 * j + r16];
    const int colbase = n0 + 64 * wn + r16;
#pragma unroll
    for (int i = 0; i < 4; i++) {
        int rowb = m0 + 64 * wm + 16 * i + qb * 4;
#pragma unroll
        for (int r = 0; r < 4; r++) {
            int row = rowb + r;
            if (row >= M) continue;
#pragma unroll
            for (int j = 0; j < 4; j++) {
                float v = acc[i][j][r] + bv[j];
                long long off = (long long)row * N + colbase + 16 * j;
                if (res)  v += res[off];
                if (relu) v = fmaxf(v, 0.f);
                if (Cf) Cf[off] = v;
                if (Cb) ((unsigned short*)Cb)[off] = f2bfu(v);
            }
        }
    }
}

// ---------------------------------------------------------------------------
// Softsign attention, bf16 in/out, fp32 math in LDS/regs.
// Block: one (b,h), 64 s-rows; K/V streamed in 64-chunks.
// ---------------------------------------------------------------------------
__global__ __launch_bounds__(256) void attn_k(
    const unsigned short* __restrict__ Q, const unsigned short* __restrict__ Kx,
    const unsigned short* __restrict__ V, unsigned short* __restrict__ O)
{
    __shared__ float qst[64][68];  // [d][s]
    __shared__ float kss[64][68];  // [d][t], reused as ss[s][t]
    __shared__ float vss[64][68];  // [t][d]
    int t  = threadIdx.x;
    int b  = blockIdx.y >> 4;
    int hh = blockIdx.y & 15;
    int s0 = blockIdx.x << 6;
    long long qbase = ((long long)(b << 10) + s0) << 10;
    int hoff = hh << 6;

#pragma unroll
    for (int i = 0; i < 4; i++) {
        int f = t + (i << 8);
        int row = f >> 4;
        int c = (f & 15) << 2;
        ushort4 qv = *(const ushort4*)(Q + qbase + ((long long)row << 10) + hoff + c);
        qst[c + 0][row] = bf2f(qv.x); qst[c + 1][row] = bf2f(qv.y);
        qst[c + 2][row] = bf2f(qv.z); qst[c + 3][row] = bf2f(qv.w);
    }

    int tmr = (t >> 4) << 2;
    int tnr = (t & 15) << 2;
    float wacc[4][4] = {};

    for (int t0 = 0; t0 < 1024; t0 += 64) {
        long long kbase = ((long long)(b << 10) + t0) << 10;
#pragma unroll
        for (int i = 0; i < 4; i++) {
            int f = t + (i << 8);
            int row = f >> 4;
            int c = (f & 15) << 2;
            ushort4 kv = *(const ushort4*)(Kx + kbase + ((long long)row << 10) + hoff + c);
            kss[c + 0][row] = bf2f(kv.x); kss[c + 1][row] = bf2f(kv.y);
            kss[c + 2][row] = bf2f(kv.z); kss[c + 3][row] = bf2f(kv.w);
            ushort4 vv = *(const ushort4*)(V + kbase + ((long long)row << 10) + hoff + c);
            vss[row][c + 0] = bf2f(vv.x); vss[row][c + 1] = bf2f(vv.y);
            vss[row][c + 2] = bf2f(vv.z); vss[row][c + 3] = bf2f(vv.w);
        }
        __syncthreads();

        float sc[4][4] = {};
#pragma unroll 8
        for (int d = 0; d < 64; d++) {
            float a[4], bb[4];
            *(float4*)a  = *(const float4*)&qst[d][tmr];
            *(float4*)bb = *(const float4*)&kss[d][tnr];
#pragma unroll
            for (int i = 0; i < 4; i++)
#pragma unroll
                for (int j = 0; j < 4; j++)
                    sc[i][j] = fmaf(a[i], bb[j], sc[i][j]);
        }
        __syncthreads();

        float (*ss)[68] = kss;
#pragma unroll
        for (int i = 0; i < 4; i++)
#pragma unroll
            for (int j = 0; j < 4; j++) {
                float v = sc[i][j] * 0.125f;
                ss[tmr + i][tnr + j] = v / (1.0f + fabsf(v));
            }
        __syncthreads();

#pragma unroll 8
        for (int tt = 0; tt < 64; tt++) {
            float av[4];
            av[0] = ss[tmr + 0][tt]; av[1] = ss[tmr + 1][tt];
            av[2] = ss[tmr + 2][tt]; av[3] = ss[tmr + 3][tt];
            float vbv[4];
            *(float4*)vbv = *(const float4*)&vss[tt][tnr];
#pragma unroll
            for (int i = 0; i < 4; i++)
#pragma unroll
                for (int j = 0; j < 4; j++)
                    wacc[i][j] = fmaf(av[i], vbv[j], wacc[i][j]);
        }
        __syncthreads();
    }

#pragma unroll
    for (int i = 0; i < 4; i++) {
        ushort4 o;
        o.x = f2bfu(wacc[i][0]); o.y = f2bfu(wacc[i][1]);
        o.z = f2bfu(wacc[i][2]); o.w = f2bfu(wacc[i][3]);
        *(ushort4*)(O + qbase + ((long long)(tmr + i) << 10) + hoff + tnr) = o;
    }
}

// ---------------------------------------------------------------------------
// Torch-style LayerNorm over D=1024 (unbiased var, eps on std), bf16 out.
// ---------------------------------------------------------------------------
__global__ __launch_bounds__(256) void layernorm_k(
    const float* __restrict__ x, const float* __restrict__ w,
    const float* __restrict__ b, unsigned short* __restrict__ y)
{
    int row = blockIdx.x;
    int t = threadIdx.x;
    float4 v = ((const float4*)(x + ((long long)row << 10)))[t];
    float s = v.x + v.y + v.z + v.w;
#pragma unroll
    for (int o = 32; o; o >>= 1) s += __shfl_down(s, o);
    __shared__ float red[4];
    __shared__ float red2[4];
    int wid = t >> 6, lane = t & 63;
    if (lane == 0) red[wid] = s;
    __syncthreads();
    float mean = (red[0] + red[1] + red[2] + red[3]) * (1.0f / 1024.0f);
    float dx = v.x - mean, dy = v.y - mean, dz = v.z - mean, dw = v.w - mean;
    float sq = dx * dx + dy * dy + dz * dz + dw * dw;
#pragma unroll
    for (int o = 32; o; o >>= 1) sq += __shfl_down(sq, o);
    if (lane == 0) red2[wid] = sq;
    __syncthreads();
    float var = (red2[0] + red2[1] + red2[2] + red2[3]) * (1.0f / 1023.0f);
    float inv = 1.0f / (sqrtf(var) + 1e-6f);
    float4 W  = ((const float4*)w)[t];
    float4 Bv = ((const float4*)b)[t];
    ushort4 o;
    o.x = f2bfu(W.x * (dx * inv) + Bv.x);
    o.y = f2bfu(W.y * (dy * inv) + Bv.y);
    o.z = f2bfu(W.z * (dz * inv) + Bv.z);
    o.w = f2bfu(W.w * (dw * inv) + Bv.w);
    ((ushort4*)(y + ((long long)row << 10)))[t] = o;
}

// ---------------------------------------------------------------------------
__global__ __launch_bounds__(256) void add_pos_k(float* __restrict__ h)
{
    int idx = blockIdx.x * 256 + threadIdx.x;
    int d = idx & 1023;
    int s = (idx >> 10) & 1023;
    int e = d & ~1;
    float div = expf(-9.210340371976184f * (float)e * (1.0f / 1024.0f));
    float arg = (float)s * div;
    float pe = (d & 1) ? cosf(arg) : sinf(arg);
    h[idx] += pe;
}

// fp32 -> bf16 elementwise (n4 = count/4)
__global__ __launch_bounds__(256) void convert_k(
    const float* __restrict__ src, unsigned short* __restrict__ dst, int n4)
{
    int i = blockIdx.x * 256 + threadIdx.x;
    if (i >= n4) return;
    float4 v = ((const float4*)src)[i];
    ushort4 o;
    o.x = f2bfu(v.x); o.y = f2bfu(v.y); o.z = f2bfu(v.z); o.w = f2bfu(v.w);
    ((ushort4*)dst)[i] = o;
}

// conv weight reorder + convert: [OC][IC][3] fp32 -> [OC][3][IC] bf16
__global__ __launch_bounds__(256) void reorder_w_k(
    const float* __restrict__ src, unsigned short* __restrict__ dst, int OC, int IC)
{
    int idx = blockIdx.x * 256 + threadIdx.x;
    if (idx >= OC * IC * 3) return;
    int k  = idx % 3;
    int ic = (idx / 3) % IC;
    int oc = idx / (3 * IC);
    dst[(oc * 3 + k) * IC + ic] = f2bfu(src[idx]);
}

__global__ __launch_bounds__(256) void meanpool_k(
    const float* __restrict__ h, float* __restrict__ p)
{
    int g = blockIdx.x * 256 + threadIdx.x;
    int b = g >> 10, d = g & 1023;
    const float* base = h + ((long long)b << 20) + d;
    float s = 0.f;
    for (int i = 0; i < 1024; i++) s += base[(long long)i << 10];
    p[g] = s * (1.0f / 1024.0f);
}

__global__ __launch_bounds__(256) void fc_k(
    const float* __restrict__ p, const float* __restrict__ w,
    const float* __restrict__ fb, float* __restrict__ out)
{
    int b = blockIdx.x, t = threadIdx.x;
    float s = 0.f;
    for (int i = t; i < 1024; i += 256) s += p[(b << 10) + i] * w[i];
#pragma unroll
    for (int o = 32; o; o >>= 1) s += __shfl_down(s, o);
    __shared__ float red[4];
    if ((t & 63) == 0) red[t >> 6] = s;
    __syncthreads();
    if (t == 0) out[b] = red[0] + red[1] + red[2] + red[3] + fb[0];
}

// ---------------------------------------------------------------------------
extern "C" void kernel_launch(void* const* d_in, const int* in_sizes, int n_in,
                              void* d_out, int out_size, void* d_ws, size_t ws_size,
                              hipStream_t stream)
{
    const float* x    = (const float*)d_in[0];
    const float* c1w  = (const float*)d_in[1];
    const float* c1b  = (const float*)d_in[2];
    const float* c2w  = (const float*)d_in[3];
    const float* c2b  = (const float*)d_in[4];
    const float* lnAw = (const float*)d_in[5];
    const float* lnAb = (const float*)d_in[6];
    const float* qw   = (const float*)d_in[7];
    const float* qbi  = (const float*)d_in[8];
    const float* kw   = (const float*)d_in[9];
    const float* kbi  = (const float*)d_in[10];
    const float* vw   = (const float*)d_in[11];
    const float* vbi  = (const float*)d_in[12];
    const float* ow   = (const float*)d_in[13];
    const float* obi  = (const float*)d_in[14];
    const float* lnBw = (const float*)d_in[15];
    const float* lnBb = (const float*)d_in[16];
    const float* f1w  = (const float*)d_in[17];
    const float* f1b  = (const float*)d_in[18];
    const float* f2w  = (const float*)d_in[19];
    const float* f2b  = (const float*)d_in[20];
    const float* fcw  = (const float*)d_in[21];
    const float* fcb  = (const float*)d_in[22];
    float* out = (float*)d_out;

    float* ws = (float*)d_ws;
    typedef __hip_bfloat16 bf;
    typedef unsigned short us;
    // workspace layout (float units); total ~75.2 MB
    float* h    = ws;                          // 4,194,304
    us* hn_b    = (us*)(ws + 4194304);         // 4M bf16
    us* q_b     = (us*)(ws + 6291456);         // 4M bf16
    us* k_b     = (us*)(ws + 8388608);         // 4M bf16
    us* v_b     = (us*)(ws + 10485760);        // 4M bf16
    us* ff_b    = q_b;                         // 8M bf16 overlays q_b,k_b
    us* wq_b    = (us*)(ws + 12582912);        // 1M bf16
    us* wk_b    = (us*)(ws + 13107200);
    us* wv_b    = (us*)(ws + 13631488);
    us* wo_b    = (us*)(ws + 14155776);
    us* wf1_b   = (us*)(ws + 14680064);        // 2M bf16
    us* wf2_b   = (us*)(ws + 15728640);        // 2M bf16
    us* xb      = (us*)(ws + 16777216);        // 271,360 bf16 (padded)
    us* h1b     = (us*)(ws + 16912896);        // 2,101,248 bf16
    us* w1t_b   = (us*)(ws + 17963520);        // 98,304 bf16
    us* w2t_b   = (us*)(ws + 18012672);        // 1,572,864 bf16
    float* pooled = ws + 18799104;             // 4,096

    // frontend conversions
    convert_k<<<dim3(257), 256, 0, stream>>>(x, xb, 65792);
    reorder_w_k<<<dim3(384),  256, 0, stream>>>(c1w, w1t_b, 512, 64);
    reorder_w_k<<<dim3(6144), 256, 0, stream>>>(c2w, w2t_b, 1024, 512);

    // conv1: M=4*1026=4104, N=512, K=192 (A = xb with row remap)
    gemm_mfma_k<<<dim3(4, 33), 256, 0, stream>>>(
        (const bf*)xb, 1026, 1028LL * 64, 64, (const bf*)w1t_b,
        c1b, nullptr, nullptr, (bf*)h1b, 4104, 512, 192, 0);
    // conv2: M=4096, N=1024, K=1536
    gemm_mfma_k<<<dim3(8, 32), 256, 0, stream>>>(
        (const bf*)h1b, 1024, 1026LL * 512, 512, (const bf*)w2t_b,
        c2b, nullptr, h, nullptr, 4096, 1024, 1536, 0);
    add_pos_k<<<dim3(16384), 256, 0, stream>>>(h);

    for (int l = 0; l < 4; l++) {
        long long wo  = (long long)l * 1048576;
        long long wo2 = (long long)l * 2097152;
        convert_k<<<dim3(1024), 256, 0, stream>>>(qw + wo,  wq_b,  262144);
        convert_k<<<dim3(1024), 256, 0, stream>>>(kw + wo,  wk_b,  262144);
        convert_k<<<dim3(1024), 256, 0, stream>>>(vw + wo,  wv_b,  262144);
        convert_k<<<dim3(1024), 256, 0, stream>>>(ow + wo,  wo_b,  262144);
        convert_k<<<dim3(2048), 256, 0, stream>>>(f1w + wo2, wf1_b, 524288);
        convert_k<<<dim3(2048), 256, 0, stream>>>(f2w + wo2, wf2_b, 524288);

        layernorm_k<<<dim3(4096), 256, 0, stream>>>(h, lnAw + l * 1024, lnAb + l * 1024, hn_b);
        gemm_mfma_k<<<dim3(8, 32), 256, 0, stream>>>(
            (const bf*)hn_b, 1 << 30, 0, 1024, (const bf*)wq_b,
            qbi + l * 1024, nullptr, nullptr, (bf*)q_b, 4096, 1024, 1024, 0);
        gemm_mfma_k<<<dim3(8, 32), 256, 0, stream>>>(
            (const bf*)hn_b, 1 << 30, 0, 1024, (const bf*)wk_b,
            kbi + l * 1024, nullptr, nullptr, (bf*)k_b, 4096, 1024, 1024, 0);
        gemm_mfma_k<<<dim3(8, 32), 256, 0, stream>>>(
            (const bf*)hn_b, 1 << 30, 0, 1024, (const bf*)wv_b,
            vbi + l * 1024, nullptr, nullptr, (bf*)v_b, 4096, 1024, 1024, 0);
        attn_k<<<dim3(16, 64), 256, 0, stream>>>(q_b, k_b, v_b, hn_b);
        gemm_mfma_k<<<dim3(8, 32), 256, 0, stream>>>(
            (const bf*)hn_b, 1 << 30, 0, 1024, (const bf*)wo_b,
            obi + l * 1024, h, h, nullptr, 4096, 1024, 1024, 0);
        layernorm_k<<<dim3(4096), 256, 0, stream>>>(h, lnBw + l * 1024, lnBb + l * 1024, hn_b);
        gemm_mfma_k<<<dim3(16, 32), 256, 0, stream>>>(
            (const bf*)hn_b, 1 << 30, 0, 1024, (const bf*)wf1_b,
            f1b + l * 2048, nullptr, nullptr, (bf*)ff_b, 4096, 2048, 1024, 1);
        gemm_mfma_k<<<dim3(8, 32), 256, 0, stream>>>(
            (const bf*)ff_b, 1 << 30, 0, 2048, (const bf*)wf2_b,
            f2b + l * 1024, h, h, nullptr, 4096, 1024, 2048, 0);
    }

    meanpool_k<<<dim3(16), 256, 0, stream>>>(h, pooled);
    fc_k<<<dim3(4), 256, 0, stream>>>(pooled, fcw, fcb, out);
}

// Round 3
// 1494.925 us; speedup vs baseline: 3.8314x; 1.7065x over previous
//
#include <hip/hip_runtime.h>
#include <hip/hip_bf16.h>
#include <math.h>

// ---------------------------------------------------------------------------
// helpers
// ---------------------------------------------------------------------------
typedef __bf16 v8bf __attribute__((ext_vector_type(8)));
typedef float  v4f  __attribute__((ext_vector_type(4)));
typedef unsigned short v8us __attribute__((ext_vector_type(8)));

__device__ __forceinline__ unsigned short f2bfu(float f) {
    unsigned u = __builtin_bit_cast(unsigned, f);
    unsigned r = (u + 0x7fffu + ((u >> 16) & 1u)) >> 16;
    return (unsigned short)r;
}
__device__ __forceinline__ float bf2f(unsigned short u) {
    unsigned x = ((unsigned)u) << 16;
    return __builtin_bit_cast(float, x);
}

#define GLDS16(g, s)                                                        \
    __builtin_amdgcn_global_load_lds(                                       \
        (const __attribute__((address_space(1))) void*)(g),                 \
        (__attribute__((address_space(3))) void*)(s), 16, 0, 0)

// ---------------------------------------------------------------------------
// bf16 MFMA GEMM: C[M,N] = A[M,K] * B[N,K]^T + bias (+res fp32) (+relu)
// A row remap: r -> A + (r/rpbA)*bstrideA + (r%rpbA)*ldA   (conv-as-GEMM)
// Outputs: Cf (fp32) and/or Cb (bf16), leading dim ldC. Columns >= ctcol0
// (when Ct != null) are instead written TRANSPOSED per batch of 1024 rows:
// Ct[(row>>10)*2^20 + (col-ctcol0)*1024 + (row&1023)]  (for attention V^T).
// 128x128 tile, BK=32, 4 waves, fragment-contiguous LDS via global_load_lds.
// ---------------------------------------------------------------------------
__global__ __launch_bounds__(256) void gemm_mfma_k(
    const __hip_bfloat16* __restrict__ A, int rpbA, long long bstrideA, int ldA,
    const __hip_bfloat16* __restrict__ B,
    const float* __restrict__ bias,
    const float* __restrict__ res,
    float* __restrict__ Cf,
    __hip_bfloat16* __restrict__ Cb,
    unsigned short* __restrict__ Ct, int ctcol0,
    int M, int N, int K, int ldC, int relu)
{
    __shared__ __align__(16) __hip_bfloat16 As[8][64][8];
    __shared__ __align__(16) __hip_bfloat16 Bs[8][64][8];
    const int t  = threadIdx.x;
    const int w  = t >> 6;
    const int l  = t & 63;
    const int m0 = blockIdx.y * 128;
    const int n0 = blockIdx.x * 128;
    const int r16 = l & 15;
    const int qb  = l >> 4;
    const int wm = w >> 1, wn = w & 1;

    const __hip_bfloat16* gA[2];
    const __hip_bfloat16* gB[2];
#pragma unroll
    for (int tt = 0; tt < 2; tt++) {
        int arow = m0 + 16 * (2 * w + tt) + r16;
        gA[tt] = A + (long long)(arow / rpbA) * bstrideA
                   + (long long)(arow % rpbA) * ldA + qb * 8;
        int brow = n0 + 16 * (2 * w + tt) + r16;
        gB[tt] = B + (long long)brow * K + qb * 8;
    }

    v4f acc[4][4];
#pragma unroll
    for (int i = 0; i < 4; i++)
#pragma unroll
        for (int j = 0; j < 4; j++) acc[i][j] = (v4f){0.f, 0.f, 0.f, 0.f};

    for (int k0 = 0; k0 < K; k0 += 32) {
        GLDS16(gA[0] + k0, &As[2 * w + 0][0][0]);
        GLDS16(gA[1] + k0, &As[2 * w + 1][0][0]);
        GLDS16(gB[0] + k0, &Bs[2 * w + 0][0][0]);
        GLDS16(gB[1] + k0, &Bs[2 * w + 1][0][0]);
        __syncthreads();
        v8bf af[4], bfr[4];
#pragma unroll
        for (int i = 0; i < 4; i++) af[i]  = *(const v8bf*)(&As[4 * wm + i][l][0]);
#pragma unroll
        for (int j = 0; j < 4; j++) bfr[j] = *(const v8bf*)(&Bs[4 * wn + j][l][0]);
        __syncthreads();
#pragma unroll
        for (int i = 0; i < 4; i++)
#pragma unroll
            for (int j = 0; j < 4; j++)
                acc[i][j] = __builtin_amdgcn_mfma_f32_16x16x32_bf16(
                    af[i], bfr[j], acc[i][j], 0, 0, 0);
    }

    float bv[4];
#pragma unroll
    for (int j = 0; j < 4; j++) bv[j] = bias[n0 + 64 * wn + 16 * j + r16];
    const int colbase = n0 + 64 * wn + r16;
#pragma unroll
    for (int i = 0; i < 4; i++) {
        int rowb = m0 + 64 * wm + 16 * i + qb * 4;
#pragma unroll
        for (int j = 0; j < 4; j++) {
            int col = colbase + 16 * j;
            float v[4];
#pragma unroll
            for (int r = 0; r < 4; r++) v[r] = acc[i][j][r] + bv[j];
            if (Ct && col >= ctcol0) {
                if (rowb + 3 < M) {
                    ushort4 o;
                    o.x = f2bfu(v[0]); o.y = f2bfu(v[1]);
                    o.z = f2bfu(v[2]); o.w = f2bfu(v[3]);
                    *(ushort4*)(Ct + ((long long)(rowb >> 10) << 20)
                                + (long long)(col - ctcol0) * 1024 + (rowb & 1023)) = o;
                }
            } else {
#pragma unroll
                for (int r = 0; r < 4; r++) {
                    int row = rowb + r;
                    if (row >= M) continue;
                    long long off = (long long)row * ldC + col;
                    float vv = v[r];
                    if (res)  vv += res[off];
                    if (relu) vv = fmaxf(vv, 0.f);
                    if (Cf) Cf[off] = vv;
                    if (Cb) ((unsigned short*)Cb)[off] = f2bfu(vv);
                }
            }
        }
    }
}

// ---------------------------------------------------------------------------
// MFMA softsign attention.
// Grid (8 s-tiles, 64 bh). Block = 4 waves; wave w owns s-rows 32w..32w+31.
// QKV: [4096][3072] bf16 (Q at col 0, K at col 1024). Vt: [4][1024 d][1024 t].
// Per 64-t chunk: QK^T (MFMA) -> softsign -> P to LDS (own rows only, no
// barrier needed) -> PV (MFMA) accumulating O in regs. O exits via LDS
// transpose for coalesced stores.
// ---------------------------------------------------------------------------
__global__ __launch_bounds__(256) void attn_mfma_k(
    const unsigned short* __restrict__ QKV,
    const unsigned short* __restrict__ Vt,
    unsigned short* __restrict__ O)
{
    // layout (ushort units): Qs [0,8192) (dead after prologue; O-buf overlays),
    // Ks [8192,12288), Vts [12288,16384), P [16384,25600) rows stride 72
    __shared__ __align__(16) unsigned short lds[25600];
    const int t = threadIdx.x, w = t >> 6, l = t & 63;
    const int bh = blockIdx.y, b = bh >> 4, h = bh & 15;
    const int s0 = blockIdx.x << 7;
    const int r16 = l & 15, q4 = l >> 4;
    const long long qrow0 = (long long)(b << 10) + s0;
    const int hoff = h << 6;

    // stage Q tile: wave w stages+reads its own 4 fragment regions
#pragma unroll
    for (int mi = 0; mi < 2; mi++)
#pragma unroll
        for (int kk = 0; kk < 2; kk++) {
            const unsigned short* g = QKV + (qrow0 + 32 * w + 16 * mi + r16) * 3072
                                      + hoff + 32 * kk + q4 * 8;
            GLDS16(g, &lds[(w * 4 + mi * 2 + kk) * 512]);
        }
    __syncthreads();
    v8bf qf[2][2];
#pragma unroll
    for (int mi = 0; mi < 2; mi++)
#pragma unroll
        for (int kk = 0; kk < 2; kk++)
            qf[mi][kk] = *(const v8bf*)&lds[(w * 4 + mi * 2 + kk) * 512 + l * 8];

    v4f oacc[2][4];
#pragma unroll
    for (int i = 0; i < 2; i++)
#pragma unroll
        for (int j = 0; j < 4; j++) oacc[i][j] = (v4f){0.f, 0.f, 0.f, 0.f};

    for (int t0 = 0; t0 < 1024; t0 += 64) {
        // stage K + Vt fragment regions (8 each); wave w stages 2w, 2w+1
#pragma unroll
        for (int rr = 0; rr < 2; rr++) {
            int r = 2 * w + rr, kk = r >> 2, j = r & 3;
            const unsigned short* gk = QKV
                + ((long long)(b << 10) + t0 + 16 * j + r16) * 3072
                + 1024 + hoff + 32 * kk + q4 * 8;
            GLDS16(gk, &lds[8192 + r * 512]);
            const unsigned short* gv = Vt + ((long long)b << 20)
                + (long long)(hoff + 16 * j + r16) * 1024 + t0 + 32 * kk + q4 * 8;
            GLDS16(gv, &lds[12288 + r * 512]);
        }
        __syncthreads();

        // QK^T
        v8bf kf[2][4];
#pragma unroll
        for (int kk = 0; kk < 2; kk++)
#pragma unroll
            for (int j = 0; j < 4; j++)
                kf[kk][j] = *(const v8bf*)&lds[8192 + (kk * 4 + j) * 512 + l * 8];
        v4f sc[2][4];
#pragma unroll
        for (int i = 0; i < 2; i++)
#pragma unroll
            for (int j = 0; j < 4; j++) sc[i][j] = (v4f){0.f, 0.f, 0.f, 0.f};
#pragma unroll
        for (int kk = 0; kk < 2; kk++)
#pragma unroll
            for (int mi = 0; mi < 2; mi++)
#pragma unroll
                for (int j = 0; j < 4; j++)
                    sc[mi][j] = __builtin_amdgcn_mfma_f32_16x16x32_bf16(
                        qf[mi][kk], kf[kk][j], sc[mi][j], 0, 0, 0);

        // softsign -> P (bf16). Each wave writes/reads ONLY its own 32 rows.
#pragma unroll
        for (int mi = 0; mi < 2; mi++)
#pragma unroll
            for (int j = 0; j < 4; j++)
#pragma unroll
                for (int r = 0; r < 4; r++) {
                    float v = sc[mi][j][r] * 0.125f;
                    float p = v * __builtin_amdgcn_rcpf(1.0f + fabsf(v));
                    lds[16384 + (32 * w + 16 * mi + q4 * 4 + r) * 72 + 16 * j + r16] = f2bfu(p);
                }

        // PV
        v8bf pf[2][2], vf[2][4];
#pragma unroll
        for (int mi = 0; mi < 2; mi++)
#pragma unroll
            for (int kk = 0; kk < 2; kk++)
                pf[mi][kk] = *(const v8bf*)&lds[16384 + (32 * w + 16 * mi + r16) * 72
                                                + 32 * kk + q4 * 8];
#pragma unroll
        for (int kk = 0; kk < 2; kk++)
#pragma unroll
            for (int j = 0; j < 4; j++)
                vf[kk][j] = *(const v8bf*)&lds[12288 + (kk * 4 + j) * 512 + l * 8];
#pragma unroll
        for (int kk = 0; kk < 2; kk++)
#pragma unroll
            for (int mi = 0; mi < 2; mi++)
#pragma unroll
                for (int j = 0; j < 4; j++)
                    oacc[mi][j] = __builtin_amdgcn_mfma_f32_16x16x32_bf16(
                        pf[mi][kk], vf[kk][j], oacc[mi][j], 0, 0, 0);
        __syncthreads();
    }

    // O -> LDS (overlay region 0), then coalesced global stores
#pragma unroll
    for (int mi = 0; mi < 2; mi++)
#pragma unroll
        for (int j = 0; j < 4; j++)
#pragma unroll
            for (int r = 0; r < 4; r++)
                lds[(32 * w + 16 * mi + q4 * 4 + r) * 72 + 16 * j + r16] =
                    f2bfu(oacc[mi][j][r]);
    __syncthreads();
    {
        int row = t >> 1, ch = (t & 1) << 5;
#pragma unroll
        for (int i = 0; i < 4; i++) {
            v8us vv = *(const v8us*)&lds[row * 72 + ch + 8 * i];
            *(v8us*)(O + (qrow0 + row) * 1024 + hoff + ch + 8 * i) = vv;
        }
    }
}

// ---------------------------------------------------------------------------
// Torch-style LayerNorm over D=1024 (unbiased var, eps on std), bf16 out.
// ---------------------------------------------------------------------------
__global__ __launch_bounds__(256) void layernorm_k(
    const float* __restrict__ x, const float* __restrict__ w,
    const float* __restrict__ b, unsigned short* __restrict__ y)
{
    int row = blockIdx.x;
    int t = threadIdx.x;
    float4 v = ((const float4*)(x + ((long long)row << 10)))[t];
    float s = v.x + v.y + v.z + v.w;
#pragma unroll
    for (int o = 32; o; o >>= 1) s += __shfl_down(s, o);
    __shared__ float red[4];
    __shared__ float red2[4];
    int wid = t >> 6, lane = t & 63;
    if (lane == 0) red[wid] = s;
    __syncthreads();
    float mean = (red[0] + red[1] + red[2] + red[3]) * (1.0f / 1024.0f);
    float dx = v.x - mean, dy = v.y - mean, dz = v.z - mean, dw = v.w - mean;
    float sq = dx * dx + dy * dy + dz * dz + dw * dw;
#pragma unroll
    for (int o = 32; o; o >>= 1) sq += __shfl_down(sq, o);
    if (lane == 0) red2[wid] = sq;
    __syncthreads();
    float var = (red2[0] + red2[1] + red2[2] + red2[3]) * (1.0f / 1023.0f);
    float inv = 1.0f / (sqrtf(var) + 1e-6f);
    float4 W  = ((const float4*)w)[t];
    float4 Bv = ((const float4*)b)[t];
    ushort4 o;
    o.x = f2bfu(W.x * (dx * inv) + Bv.x);
    o.y = f2bfu(W.y * (dy * inv) + Bv.y);
    o.z = f2bfu(W.z * (dz * inv) + Bv.z);
    o.w = f2bfu(W.w * (dw * inv) + Bv.w);
    ((ushort4*)(y + ((long long)row << 10)))[t] = o;
}

// ---------------------------------------------------------------------------
__global__ __launch_bounds__(256) void add_pos_k(float* __restrict__ h)
{
    int idx = blockIdx.x * 256 + threadIdx.x;
    int d = idx & 1023;
    int s = (idx >> 10) & 1023;
    int e = d & ~1;
    float div = expf(-9.210340371976184f * (float)e * (1.0f / 1024.0f));
    float arg = (float)s * div;
    float pe = (d & 1) ? cosf(arg) : sinf(arg);
    h[idx] += pe;
}

__global__ __launch_bounds__(256) void convert_k(
    const float* __restrict__ src, unsigned short* __restrict__ dst, int n4)
{
    int i = blockIdx.x * 256 + threadIdx.x;
    if (i >= n4) return;
    float4 v = ((const float4*)src)[i];
    ushort4 o;
    o.x = f2bfu(v.x); o.y = f2bfu(v.y); o.z = f2bfu(v.z); o.w = f2bfu(v.w);
    ((ushort4*)dst)[i] = o;
}

__global__ __launch_bounds__(256) void concat3_k(
    const float* __restrict__ a, const float* __restrict__ b,
    const float* __restrict__ c, float* __restrict__ o)
{
    int i = blockIdx.x * 256 + threadIdx.x;  // 0..3071
    o[i] = (i < 1024) ? a[i] : ((i < 2048) ? b[i - 1024] : c[i - 2048]);
}

__global__ __launch_bounds__(256) void reorder_w_k(
    const float* __restrict__ src, unsigned short* __restrict__ dst, int OC, int IC)
{
    int idx = blockIdx.x * 256 + threadIdx.x;
    if (idx >= OC * IC * 3) return;
    int k  = idx % 3;
    int ic = (idx / 3) % IC;
    int oc = idx / (3 * IC);
    dst[(oc * 3 + k) * IC + ic] = f2bfu(src[idx]);
}

__global__ __launch_bounds__(256) void meanpool_k(
    const float* __restrict__ h, float* __restrict__ p)
{
    int g = blockIdx.x * 256 + threadIdx.x;
    int b = g >> 10, d = g & 1023;
    const float* base = h + ((long long)b << 20) + d;
    float s = 0.f;
    for (int i = 0; i < 1024; i++) s += base[(long long)i << 10];
    p[g] = s * (1.0f / 1024.0f);
}

__global__ __launch_bounds__(256) void fc_k(
    const float* __restrict__ p, const float* __restrict__ w,
    const float* __restrict__ fb, float* __restrict__ out)
{
    int b = blockIdx.x, t = threadIdx.x;
    float s = 0.f;
    for (int i = t; i < 1024; i += 256) s += p[(b << 10) + i] * w[i];
#pragma unroll
    for (int o = 32; o; o >>= 1) s += __shfl_down(s, o);
    __shared__ float red[4];
    if ((t & 63) == 0) red[t >> 6] = s;
    __syncthreads();
    if (t == 0) out[b] = red[0] + red[1] + red[2] + red[3] + fb[0];
}

// ---------------------------------------------------------------------------
extern "C" void kernel_launch(void* const* d_in, const int* in_sizes, int n_in,
                              void* d_out, int out_size, void* d_ws, size_t ws_size,
                              hipStream_t stream)
{
    const float* x    = (const float*)d_in[0];
    const float* c1w  = (const float*)d_in[1];
    const float* c1b  = (const float*)d_in[2];
    const float* c2w  = (const float*)d_in[3];
    const float* c2b  = (const float*)d_in[4];
    const float* lnAw = (const float*)d_in[5];
    const float* lnAb = (const float*)d_in[6];
    const float* qw   = (const float*)d_in[7];
    const float* qbi  = (const float*)d_in[8];
    const float* kw   = (const float*)d_in[9];
    const float* kbi  = (const float*)d_in[10];
    const float* vw   = (const float*)d_in[11];
    const float* vbi  = (const float*)d_in[12];
    const float* ow   = (const float*)d_in[13];
    const float* obi  = (const float*)d_in[14];
    const float* lnBw = (const float*)d_in[15];
    const float* lnBb = (const float*)d_in[16];
    const float* f1w  = (const float*)d_in[17];
    const float* f1b  = (const float*)d_in[18];
    const float* f2w  = (const float*)d_in[19];
    const float* f2b  = (const float*)d_in[20];
    const float* fcw  = (const float*)d_in[21];
    const float* fcb  = (const float*)d_in[22];
    float* out = (float*)d_out;

    float* ws = (float*)d_ws;
    typedef __hip_bfloat16 bf;
    typedef unsigned short us;
    // workspace layout (float units); total ~83.6 MB
    float* h    = ws;                          // 4,194,304 f
    us* hn_b    = (us*)(ws + 4194304);         // 4M us
    us* qkv_b   = (us*)(ws + 6291456);         // [4096][3072] us
    us* ff_b    = qkv_b;                       // [4096][2048] us overlay
    us* wq_b    = (us*)(ws + 12582912);        // 1M us (wq|wk|wv adjacent!)
    us* wk_b    = (us*)(ws + 13107200);
    us* wv_b    = (us*)(ws + 13631488);
    us* wo_b    = (us*)(ws + 14155776);
    us* wf1_b   = (us*)(ws + 14680064);        // 2M us
    us* wf2_b   = (us*)(ws + 15728640);        // 2M us
    us* xb      = (us*)(ws + 16777216);
    us* h1b     = (us*)(ws + 16912896);
    us* w1t_b   = (us*)(ws + 17963520);
    us* w2t_b   = (us*)(ws + 18012672);
    float* pooled = ws + 18799104;             // 4,096 f
    us* Vt      = (us*)(ws + 18803200);        // [4][1024 d][1024 t] us
    float* bqkv = ws + 20900352;               // 3,072 f

    convert_k<<<dim3(257), 256, 0, stream>>>(x, xb, 65792);
    reorder_w_k<<<dim3(384),  256, 0, stream>>>(c1w, w1t_b, 512, 64);
    reorder_w_k<<<dim3(6144), 256, 0, stream>>>(c2w, w2t_b, 1024, 512);

    // conv1: M=4104, N=512, K=192
    gemm_mfma_k<<<dim3(4, 33), 256, 0, stream>>>(
        (const bf*)xb, 1026, 1028LL * 64, 64, (const bf*)w1t_b,
        c1b, nullptr, nullptr, (bf*)h1b, nullptr, 0, 4104, 512, 192, 512, 0);
    // conv2: M=4096, N=1024, K=1536
    gemm_mfma_k<<<dim3(8, 32), 256, 0, stream>>>(
        (const bf*)h1b, 1024, 1026LL * 512, 512, (const bf*)w2t_b,
        c2b, nullptr, h, nullptr, nullptr, 0, 4096, 1024, 1536, 1024, 0);
    add_pos_k<<<dim3(16384), 256, 0, stream>>>(h);

    for (int l = 0; l < 4; l++) {
        long long wo  = (long long)l * 1048576;
        long long wo2 = (long long)l * 2097152;
        convert_k<<<dim3(1024), 256, 0, stream>>>(qw + wo,  wq_b,  262144);
        convert_k<<<dim3(1024), 256, 0, stream>>>(kw + wo,  wk_b,  262144);
        convert_k<<<dim3(1024), 256, 0, stream>>>(vw + wo,  wv_b,  262144);
        convert_k<<<dim3(1024), 256, 0, stream>>>(ow + wo,  wo_b,  262144);
        convert_k<<<dim3(2048), 256, 0, stream>>>(f1w + wo2, wf1_b, 524288);
        convert_k<<<dim3(2048), 256, 0, stream>>>(f2w + wo2, wf2_b, 524288);
        concat3_k<<<dim3(12), 256, 0, stream>>>(qbi + l * 1024, kbi + l * 1024,
                                                vbi + l * 1024, bqkv);

        layernorm_k<<<dim3(4096), 256, 0, stream>>>(h, lnAw + l * 1024, lnAb + l * 1024, hn_b);
        // fused QKV: N=3072; cols >=2048 (V) written transposed into Vt
        gemm_mfma_k<<<dim3(24, 32), 256, 0, stream>>>(
            (const bf*)hn_b, 1 << 30, 0, 1024, (const bf*)wq_b,
            bqkv, nullptr, nullptr, (bf*)qkv_b, Vt, 2048, 4096, 3072, 1024, 3072, 0);
        attn_mfma_k<<<dim3(8, 64), 256, 0, stream>>>(qkv_b, Vt, hn_b);
        gemm_mfma_k<<<dim3(8, 32), 256, 0, stream>>>(
            (const bf*)hn_b, 1 << 30, 0, 1024, (const bf*)wo_b,
            obi + l * 1024, h, h, nullptr, nullptr, 0, 4096, 1024, 1024, 1024, 0);
        layernorm_k<<<dim3(4096), 256, 0, stream>>>(h, lnBw + l * 1024, lnBb + l * 1024, hn_b);
        gemm_mfma_k<<<dim3(16, 32), 256, 0, stream>>>(
            (const bf*)hn_b, 1 << 30, 0, 1024, (const bf*)wf1_b,
            f1b + l * 2048, nullptr, nullptr, (bf*)ff_b, nullptr, 0, 4096, 2048, 1024, 2048, 1);
        gemm_mfma_k<<<dim3(8, 32), 256, 0, stream>>>(
            (const bf*)ff_b, 1 << 30, 0, 2048, (const bf*)wf2_b,
            f2b + l * 1024, h, h, nullptr, nullptr, 0, 4096, 1024, 2048, 1024, 0);
    }

    meanpool_k<<<dim3(16), 256, 0, stream>>>(h, pooled);
    fc_k<<<dim3(4), 256, 0, stream>>>(pooled, fcw, fcb, out);
}

// Round 4
// 1446.848 us; speedup vs baseline: 3.9588x; 1.0332x over previous
//
#include <hip/hip_runtime.h>
#include <hip/hip_bf16.h>
#include <math.h>

// ---------------------------------------------------------------------------
// helpers
// ---------------------------------------------------------------------------
typedef __bf16 v8bf __attribute__((ext_vector_type(8)));
typedef float  v4f  __attribute__((ext_vector_type(4)));
typedef unsigned short v8us __attribute__((ext_vector_type(8)));

__device__ __forceinline__ unsigned short f2bfu(float f) {
    unsigned u = __builtin_bit_cast(unsigned, f);
    unsigned r = (u + 0x7fffu + ((u >> 16) & 1u)) >> 16;
    return (unsigned short)r;
}
__device__ __forceinline__ float bf2f(unsigned short u) {
    unsigned x = ((unsigned)u) << 16;
    return __builtin_bit_cast(float, x);
}

#define GLDS16(g, s)                                                        \
    __builtin_amdgcn_global_load_lds(                                       \
        (const __attribute__((address_space(1))) void*)(g),                 \
        (__attribute__((address_space(3))) void*)(s), 16, 0, 0)

// ---------------------------------------------------------------------------
// bf16 MFMA GEMM: C[M,N] = A[M,K] * B[N,K]^T + bias (+res fp32) (+relu)
// A row remap: r -> A + (r/rpbA)*bstrideA + (r%rpbA)*ldA   (conv-as-GEMM)
// Outputs: Cf (fp32) and/or Cb (bf16), ld ldC; cols >= ctcol0 (Ct!=null) go
// TRANSPOSED to Ct[(row>>10)<<20 + (col-ctcol0)*1024 + (row&1023)] (attn V^T).
// 128x128 tile, BK=32, 4 waves, fragment-contiguous LDS via global_load_lds.
// DOUBLE-BUFFERED: prefetch tile k+1 into buf^1 before consuming buf; the
// barrier's vmcnt(0) drain then overlaps the whole iteration's compute.
// XCD m-slab swizzle: bid -> (bid%8)*(nb/8)+bid/8 so each XCD reads a
// contiguous m-slab of A (cuts cross-XCD L2 duplication).
// ---------------------------------------------------------------------------
__global__ __launch_bounds__(256) void gemm_mfma_k(
    const __hip_bfloat16* __restrict__ A, int rpbA, long long bstrideA, int ldA,
    const __hip_bfloat16* __restrict__ B,
    const float* __restrict__ bias,
    const float* __restrict__ res,
    float* __restrict__ Cf,
    __hip_bfloat16* __restrict__ Cb,
    unsigned short* __restrict__ Ct, int ctcol0,
    int M, int N, int K, int ldC, int relu)
{
    __shared__ __align__(16) __hip_bfloat16 As[2][8][64][8];
    __shared__ __align__(16) __hip_bfloat16 Bs[2][8][64][8];
    const int t  = threadIdx.x;
    const int w  = t >> 6;
    const int l  = t & 63;

    int bx = blockIdx.x, by = blockIdx.y;
    {
        int nbx = gridDim.x;
        int nb  = nbx * gridDim.y;
        if ((nb & 7) == 0) {
            int bid = by * nbx + bx;
            int nid = (bid & 7) * (nb >> 3) + (bid >> 3);
            by = nid / nbx;
            bx = nid - by * nbx;
        }
    }
    const int m0 = by * 128;
    const int n0 = bx * 128;
    const int r16 = l & 15;
    const int qb  = l >> 4;
    const int wm = w >> 1, wn = w & 1;

    const __hip_bfloat16* gA[2];
    const __hip_bfloat16* gB[2];
#pragma unroll
    for (int tt = 0; tt < 2; tt++) {
        int arow = m0 + 16 * (2 * w + tt) + r16;
        gA[tt] = A + (long long)(arow / rpbA) * bstrideA
                   + (long long)(arow % rpbA) * ldA + qb * 8;
        int brow = n0 + 16 * (2 * w + tt) + r16;
        gB[tt] = B + (long long)brow * K + qb * 8;
    }

    v4f acc[4][4];
#pragma unroll
    for (int i = 0; i < 4; i++)
#pragma unroll
        for (int j = 0; j < 4; j++) acc[i][j] = (v4f){0.f, 0.f, 0.f, 0.f};

    // prologue: stage tile 0 into buf 0
    GLDS16(gA[0], &As[0][2 * w + 0][0][0]);
    GLDS16(gA[1], &As[0][2 * w + 1][0][0]);
    GLDS16(gB[0], &Bs[0][2 * w + 0][0][0]);
    GLDS16(gB[1], &Bs[0][2 * w + 1][0][0]);
    __syncthreads();

    int cur = 0;
    for (int k0 = 32; k0 < K; k0 += 32) {
        // prefetch next tile into the other buffer (not waited here)
        GLDS16(gA[0] + k0, &As[cur ^ 1][2 * w + 0][0][0]);
        GLDS16(gA[1] + k0, &As[cur ^ 1][2 * w + 1][0][0]);
        GLDS16(gB[0] + k0, &Bs[cur ^ 1][2 * w + 0][0][0]);
        GLDS16(gB[1] + k0, &Bs[cur ^ 1][2 * w + 1][0][0]);
        v8bf af[4], bfr[4];
#pragma unroll
        for (int i = 0; i < 4; i++) af[i]  = *(const v8bf*)(&As[cur][4 * wm + i][l][0]);
#pragma unroll
        for (int j = 0; j < 4; j++) bfr[j] = *(const v8bf*)(&Bs[cur][4 * wn + j][l][0]);
#pragma unroll
        for (int i = 0; i < 4; i++)
#pragma unroll
            for (int j = 0; j < 4; j++)
                acc[i][j] = __builtin_amdgcn_mfma_f32_16x16x32_bf16(
                    af[i], bfr[j], acc[i][j], 0, 0, 0);
        __syncthreads();
        cur ^= 1;
    }
    {
        v8bf af[4], bfr[4];
#pragma unroll
        for (int i = 0; i < 4; i++) af[i]  = *(const v8bf*)(&As[cur][4 * wm + i][l][0]);
#pragma unroll
        for (int j = 0; j < 4; j++) bfr[j] = *(const v8bf*)(&Bs[cur][4 * wn + j][l][0]);
#pragma unroll
        for (int i = 0; i < 4; i++)
#pragma unroll
            for (int j = 0; j < 4; j++)
                acc[i][j] = __builtin_amdgcn_mfma_f32_16x16x32_bf16(
                    af[i], bfr[j], acc[i][j], 0, 0, 0);
    }

    float bv[4];
#pragma unroll
    for (int j = 0; j < 4; j++) bv[j] = bias[n0 + 64 * wn + 16 * j + r16];
    const int colbase = n0 + 64 * wn + r16;
#pragma unroll
    for (int i = 0; i < 4; i++) {
        int rowb = m0 + 64 * wm + 16 * i + qb * 4;
#pragma unroll
        for (int j = 0; j < 4; j++) {
            int col = colbase + 16 * j;
            float v[4];
#pragma unroll
            for (int r = 0; r < 4; r++) v[r] = acc[i][j][r] + bv[j];
            if (Ct && col >= ctcol0) {
                if (rowb + 3 < M) {
                    ushort4 o;
                    o.x = f2bfu(v[0]); o.y = f2bfu(v[1]);
                    o.z = f2bfu(v[2]); o.w = f2bfu(v[3]);
                    *(ushort4*)(Ct + ((long long)(rowb >> 10) << 20)
                                + (long long)(col - ctcol0) * 1024 + (rowb & 1023)) = o;
                }
            } else {
#pragma unroll
                for (int r = 0; r < 4; r++) {
                    int row = rowb + r;
                    if (row >= M) continue;
                    long long off = (long long)row * ldC + col;
                    float vv = v[r];
                    if (res)  vv += res[off];
                    if (relu) vv = fmaxf(vv, 0.f);
                    if (Cf) Cf[off] = vv;
                    if (Cb) ((unsigned short*)Cb)[off] = f2bfu(vv);
                }
            }
        }
    }
}

// ---------------------------------------------------------------------------
// MFMA softsign attention (unchanged from R3).
// ---------------------------------------------------------------------------
__global__ __launch_bounds__(256) void attn_mfma_k(
    const unsigned short* __restrict__ QKV,
    const unsigned short* __restrict__ Vt,
    unsigned short* __restrict__ O)
{
    __shared__ __align__(16) unsigned short lds[25600];
    const int t = threadIdx.x, w = t >> 6, l = t & 63;
    const int bh = blockIdx.y, b = bh >> 4, h = bh & 15;
    const int s0 = blockIdx.x << 7;
    const int r16 = l & 15, q4 = l >> 4;
    const long long qrow0 = (long long)(b << 10) + s0;
    const int hoff = h << 6;

#pragma unroll
    for (int mi = 0; mi < 2; mi++)
#pragma unroll
        for (int kk = 0; kk < 2; kk++) {
            const unsigned short* g = QKV + (qrow0 + 32 * w + 16 * mi + r16) * 3072
                                      + hoff + 32 * kk + q4 * 8;
            GLDS16(g, &lds[(w * 4 + mi * 2 + kk) * 512]);
        }
    __syncthreads();
    v8bf qf[2][2];
#pragma unroll
    for (int mi = 0; mi < 2; mi++)
#pragma unroll
        for (int kk = 0; kk < 2; kk++)
            qf[mi][kk] = *(const v8bf*)&lds[(w * 4 + mi * 2 + kk) * 512 + l * 8];

    v4f oacc[2][4];
#pragma unroll
    for (int i = 0; i < 2; i++)
#pragma unroll
        for (int j = 0; j < 4; j++) oacc[i][j] = (v4f){0.f, 0.f, 0.f, 0.f};

    for (int t0 = 0; t0 < 1024; t0 += 64) {
#pragma unroll
        for (int rr = 0; rr < 2; rr++) {
            int r = 2 * w + rr, kk = r >> 2, j = r & 3;
            const unsigned short* gk = QKV
                + ((long long)(b << 10) + t0 + 16 * j + r16) * 3072
                + 1024 + hoff + 32 * kk + q4 * 8;
            GLDS16(gk, &lds[8192 + r * 512]);
            const unsigned short* gv = Vt + ((long long)b << 20)
                + (long long)(hoff + 16 * j + r16) * 1024 + t0 + 32 * kk + q4 * 8;
            GLDS16(gv, &lds[12288 + r * 512]);
        }
        __syncthreads();

        v8bf kf[2][4];
#pragma unroll
        for (int kk = 0; kk < 2; kk++)
#pragma unroll
            for (int j = 0; j < 4; j++)
                kf[kk][j] = *(const v8bf*)&lds[8192 + (kk * 4 + j) * 512 + l * 8];
        v4f sc[2][4];
#pragma unroll
        for (int i = 0; i < 2; i++)
#pragma unroll
            for (int j = 0; j < 4; j++) sc[i][j] = (v4f){0.f, 0.f, 0.f, 0.f};
#pragma unroll
        for (int kk = 0; kk < 2; kk++)
#pragma unroll
            for (int mi = 0; mi < 2; mi++)
#pragma unroll
                for (int j = 0; j < 4; j++)
                    sc[mi][j] = __builtin_amdgcn_mfma_f32_16x16x32_bf16(
                        qf[mi][kk], kf[kk][j], sc[mi][j], 0, 0, 0);

#pragma unroll
        for (int mi = 0; mi < 2; mi++)
#pragma unroll
            for (int j = 0; j < 4; j++)
#pragma unroll
                for (int r = 0; r < 4; r++) {
                    float v = sc[mi][j][r] * 0.125f;
                    float p = v * __builtin_amdgcn_rcpf(1.0f + fabsf(v));
                    lds[16384 + (32 * w + 16 * mi + q4 * 4 + r) * 72 + 16 * j + r16] = f2bfu(p);
                }

        v8bf pf[2][2], vf[2][4];
#pragma unroll
        for (int mi = 0; mi < 2; mi++)
#pragma unroll
            for (int kk = 0; kk < 2; kk++)
                pf[mi][kk] = *(const v8bf*)&lds[16384 + (32 * w + 16 * mi + r16) * 72
                                                + 32 * kk + q4 * 8];
#pragma unroll
        for (int kk = 0; kk < 2; kk++)
#pragma unroll
            for (int j = 0; j < 4; j++)
                vf[kk][j] = *(const v8bf*)&lds[12288 + (kk * 4 + j) * 512 + l * 8];
#pragma unroll
        for (int kk = 0; kk < 2; kk++)
#pragma unroll
            for (int mi = 0; mi < 2; mi++)
#pragma unroll
                for (int j = 0; j < 4; j++)
                    oacc[mi][j] = __builtin_amdgcn_mfma_f32_16x16x32_bf16(
                        pf[mi][kk], vf[kk][j], oacc[mi][j], 0, 0, 0);
        __syncthreads();
    }

#pragma unroll
    for (int mi = 0; mi < 2; mi++)
#pragma unroll
        for (int j = 0; j < 4; j++)
#pragma unroll
            for (int r = 0; r < 4; r++)
                lds[(32 * w + 16 * mi + q4 * 4 + r) * 72 + 16 * j + r16] =
                    f2bfu(oacc[mi][j][r]);
    __syncthreads();
    {
        int row = t >> 1, ch = (t & 1) << 5;
#pragma unroll
        for (int i = 0; i < 4; i++) {
            v8us vv = *(const v8us*)&lds[row * 72 + ch + 8 * i];
            *(v8us*)(O + (qrow0 + row) * 1024 + hoff + ch + 8 * i) = vv;
        }
    }
}

// ---------------------------------------------------------------------------
__global__ __launch_bounds__(256) void layernorm_k(
    const float* __restrict__ x, const float* __restrict__ w,
    const float* __restrict__ b, unsigned short* __restrict__ y)
{
    int row = blockIdx.x;
    int t = threadIdx.x;
    float4 v = ((const float4*)(x + ((long long)row << 10)))[t];
    float s = v.x + v.y + v.z + v.w;
#pragma unroll
    for (int o = 32; o; o >>= 1) s += __shfl_down(s, o);
    __shared__ float red[4];
    __shared__ float red2[4];
    int wid = t >> 6, lane = t & 63;
    if (lane == 0) red[wid] = s;
    __syncthreads();
    float mean = (red[0] + red[1] + red[2] + red[3]) * (1.0f / 1024.0f);
    float dx = v.x - mean, dy = v.y - mean, dz = v.z - mean, dw = v.w - mean;
    float sq = dx * dx + dy * dy + dz * dz + dw * dw;
#pragma unroll
    for (int o = 32; o; o >>= 1) sq += __shfl_down(sq, o);
    if (lane == 0) red2[wid] = sq;
    __syncthreads();
    float var = (red2[0] + red2[1] + red2[2] + red2[3]) * (1.0f / 1023.0f);
    float inv = 1.0f / (sqrtf(var) + 1e-6f);
    float4 W  = ((const float4*)w)[t];
    float4 Bv = ((const float4*)b)[t];
    ushort4 o;
    o.x = f2bfu(W.x * (dx * inv) + Bv.x);
    o.y = f2bfu(W.y * (dy * inv) + Bv.y);
    o.z = f2bfu(W.z * (dz * inv) + Bv.z);
    o.w = f2bfu(W.w * (dw * inv) + Bv.w);
    ((ushort4*)(y + ((long long)row << 10)))[t] = o;
}

// ---------------------------------------------------------------------------
__global__ __launch_bounds__(256) void add_pos_k(float* __restrict__ h)
{
    int idx = blockIdx.x * 256 + threadIdx.x;
    int d = idx & 1023;
    int s = (idx >> 10) & 1023;
    int e = d & ~1;
    float div = expf(-9.210340371976184f * (float)e * (1.0f / 1024.0f));
    float arg = (float)s * div;
    float pe = (d & 1) ? cosf(arg) : sinf(arg);
    h[idx] += pe;
}

__global__ __launch_bounds__(256) void convert_k(
    const float* __restrict__ src, unsigned short* __restrict__ dst, int n4)
{
    int i = blockIdx.x * 256 + threadIdx.x;
    if (i >= n4) return;
    float4 v = ((const float4*)src)[i];
    ushort4 o;
    o.x = f2bfu(v.x); o.y = f2bfu(v.y); o.z = f2bfu(v.z); o.w = f2bfu(v.w);
    ((ushort4*)dst)[i] = o;
}

// One launch converts all 6 weight matrices of a layer into the contiguous
// bf16 region starting at wq_b. idx = float4 index in [0, 2^21).
// regions (256K float4 each): q,k,v,o,f1_lo,f1_hi,f2_lo,f2_hi.
__global__ __launch_bounds__(256) void convert_layer_k(
    const float* __restrict__ q, const float* __restrict__ k,
    const float* __restrict__ v, const float* __restrict__ o,
    const float* __restrict__ f1, const float* __restrict__ f2,
    unsigned short* __restrict__ dst)
{
    int idx = blockIdx.x * 256 + threadIdx.x;
    int region = idx >> 18;
    int r = idx & 0x3FFFF;
    const float* src;
    switch (region) {
        case 0: src = q; break;
        case 1: src = k; break;
        case 2: src = v; break;
        case 3: src = o; break;
        case 4: src = f1; break;
        case 5: src = f1 + 1048576; break;
        case 6: src = f2; break;
        default: src = f2 + 1048576; break;
    }
    float4 vv = ((const float4*)src)[r];
    ushort4 ov;
    ov.x = f2bfu(vv.x); ov.y = f2bfu(vv.y); ov.z = f2bfu(vv.z); ov.w = f2bfu(vv.w);
    ((ushort4*)dst)[(region << 18) + r] = ov;
}

__global__ __launch_bounds__(256) void concat3_k(
    const float* __restrict__ a, const float* __restrict__ b,
    const float* __restrict__ c, float* __restrict__ o)
{
    int i = blockIdx.x * 256 + threadIdx.x;
    o[i] = (i < 1024) ? a[i] : ((i < 2048) ? b[i - 1024] : c[i - 2048]);
}

__global__ __launch_bounds__(256) void reorder_w_k(
    const float* __restrict__ src, unsigned short* __restrict__ dst, int OC, int IC)
{
    int idx = blockIdx.x * 256 + threadIdx.x;
    if (idx >= OC * IC * 3) return;
    int k  = idx % 3;
    int ic = (idx / 3) % IC;
    int oc = idx / (3 * IC);
    dst[(oc * 3 + k) * IC + ic] = f2bfu(src[idx]);
}

__global__ __launch_bounds__(256) void meanpool_k(
    const float* __restrict__ h, float* __restrict__ p)
{
    int g = blockIdx.x * 256 + threadIdx.x;
    int b = g >> 10, d = g & 1023;
    const float* base = h + ((long long)b << 20) + d;
    float s = 0.f;
    for (int i = 0; i < 1024; i++) s += base[(long long)i << 10];
    p[g] = s * (1.0f / 1024.0f);
}

__global__ __launch_bounds__(256) void fc_k(
    const float* __restrict__ p, const float* __restrict__ w,
    const float* __restrict__ fb, float* __restrict__ out)
{
    int b = blockIdx.x, t = threadIdx.x;
    float s = 0.f;
    for (int i = t; i < 1024; i += 256) s += p[(b << 10) + i] * w[i];
#pragma unroll
    for (int o = 32; o; o >>= 1) s += __shfl_down(s, o);
    __shared__ float red[4];
    if ((t & 63) == 0) red[t >> 6] = s;
    __syncthreads();
    if (t == 0) out[b] = red[0] + red[1] + red[2] + red[3] + fb[0];
}

// ---------------------------------------------------------------------------
extern "C" void kernel_launch(void* const* d_in, const int* in_sizes, int n_in,
                              void* d_out, int out_size, void* d_ws, size_t ws_size,
                              hipStream_t stream)
{
    const float* x    = (const float*)d_in[0];
    const float* c1w  = (const float*)d_in[1];
    const float* c1b  = (const float*)d_in[2];
    const float* c2w  = (const float*)d_in[3];
    const float* c2b  = (const float*)d_in[4];
    const float* lnAw = (const float*)d_in[5];
    const float* lnAb = (const float*)d_in[6];
    const float* qw   = (const float*)d_in[7];
    const float* qbi  = (const float*)d_in[8];
    const float* kw   = (const float*)d_in[9];
    const float* kbi  = (const float*)d_in[10];
    const float* vw   = (const float*)d_in[11];
    const float* vbi  = (const float*)d_in[12];
    const float* ow   = (const float*)d_in[13];
    const float* obi  = (const float*)d_in[14];
    const float* lnBw = (const float*)d_in[15];
    const float* lnBb = (const float*)d_in[16];
    const float* f1w  = (const float*)d_in[17];
    const float* f1b  = (const float*)d_in[18];
    const float* f2w  = (const float*)d_in[19];
    const float* f2b  = (const float*)d_in[20];
    const float* fcw  = (const float*)d_in[21];
    const float* fcb  = (const float*)d_in[22];
    float* out = (float*)d_out;

    float* ws = (float*)d_ws;
    typedef __hip_bfloat16 bf;
    typedef unsigned short us;
    float* h    = ws;                          // 4,194,304 f
    us* hn_b    = (us*)(ws + 4194304);         // 4M us
    us* qkv_b   = (us*)(ws + 6291456);         // [4096][3072] us
    us* ff_b    = qkv_b;                       // [4096][2048] us overlay
    us* wq_b    = (us*)(ws + 12582912);        // contiguous: q,k,v,o,f1,f2
    us* wo_b    = (us*)(ws + 14155776);
    us* wf1_b   = (us*)(ws + 14680064);
    us* wf2_b   = (us*)(ws + 15728640);
    us* xb      = (us*)(ws + 16777216);
    us* h1b     = (us*)(ws + 16912896);
    us* w1t_b   = (us*)(ws + 17963520);
    us* w2t_b   = (us*)(ws + 18012672);
    float* pooled = ws + 18799104;             // 4,096 f
    us* Vt      = (us*)(ws + 18803200);        // [4][1024 d][1024 t] us
    float* bqkv = ws + 20900352;               // 3,072 f

    convert_k<<<dim3(257), 256, 0, stream>>>(x, xb, 65792);
    reorder_w_k<<<dim3(384),  256, 0, stream>>>(c1w, w1t_b, 512, 64);
    reorder_w_k<<<dim3(6144), 256, 0, stream>>>(c2w, w2t_b, 1024, 512);

    // conv1: M=4104, N=512, K=192
    gemm_mfma_k<<<dim3(4, 33), 256, 0, stream>>>(
        (const bf*)xb, 1026, 1028LL * 64, 64, (const bf*)w1t_b,
        c1b, nullptr, nullptr, (bf*)h1b, nullptr, 0, 4104, 512, 192, 512, 0);
    // conv2: M=4096, N=1024, K=1536
    gemm_mfma_k<<<dim3(8, 32), 256, 0, stream>>>(
        (const bf*)h1b, 1024, 1026LL * 512, 512, (const bf*)w2t_b,
        c2b, nullptr, h, nullptr, nullptr, 0, 4096, 1024, 1536, 1024, 0);
    add_pos_k<<<dim3(16384), 256, 0, stream>>>(h);

    for (int l = 0; l < 4; l++) {
        long long wo  = (long long)l * 1048576;
        long long wo2 = (long long)l * 2097152;
        convert_layer_k<<<dim3(8192), 256, 0, stream>>>(
            qw + wo, kw + wo, vw + wo, ow + wo, f1w + wo2, f2w + wo2, wq_b);
        concat3_k<<<dim3(12), 256, 0, stream>>>(qbi + l * 1024, kbi + l * 1024,
                                                vbi + l * 1024, bqkv);

        layernorm_k<<<dim3(4096), 256, 0, stream>>>(h, lnAw + l * 1024, lnAb + l * 1024, hn_b);
        // fused QKV: N=3072; cols >=2048 (V) written transposed into Vt
        gemm_mfma_k<<<dim3(24, 32), 256, 0, stream>>>(
            (const bf*)hn_b, 1 << 30, 0, 1024, (const bf*)wq_b,
            bqkv, nullptr, nullptr, (bf*)qkv_b, Vt, 2048, 4096, 3072, 1024, 3072, 0);
        attn_mfma_k<<<dim3(8, 64), 256, 0, stream>>>(qkv_b, Vt, hn_b);
        gemm_mfma_k<<<dim3(8, 32), 256, 0, stream>>>(
            (const bf*)hn_b, 1 << 30, 0, 1024, (const bf*)wo_b,
            obi + l * 1024, h, h, nullptr, nullptr, 0, 4096, 1024, 1024, 1024, 0);
        layernorm_k<<<dim3(4096), 256, 0, stream>>>(h, lnBw + l * 1024, lnBb + l * 1024, hn_b);
        gemm_mfma_k<<<dim3(16, 32), 256, 0, stream>>>(
            (const bf*)hn_b, 1 << 30, 0, 1024, (const bf*)wf1_b,
            f1b + l * 2048, nullptr, nullptr, (bf*)ff_b, nullptr, 0, 4096, 2048, 1024, 2048, 1);
        gemm_mfma_k<<<dim3(8, 32), 256, 0, stream>>>(
            (const bf*)ff_b, 1 << 30, 0, 2048, (const bf*)wf2_b,
            f2b + l * 1024, h, h, nullptr, nullptr, 0, 4096, 1024, 2048, 1024, 0);
    }

    meanpool_k<<<dim3(16), 256, 0, stream>>>(h, pooled);
    fc_k<<<dim3(4), 256, 0, stream>>>(pooled, fcw, fcb, out);
}

// Round 5
// 1397.813 us; speedup vs baseline: 4.0976x; 1.0351x over previous
//
#include <hip/hip_runtime.h>
#include <hip/hip_bf16.h>
#include <math.h>

// ---------------------------------------------------------------------------
// helpers
// ---------------------------------------------------------------------------
typedef __bf16 v8bf __attribute__((ext_vector_type(8)));
typedef float  v4f  __attribute__((ext_vector_type(4)));
typedef unsigned short v8us __attribute__((ext_vector_type(8)));

__device__ __forceinline__ unsigned short f2bfu(float f) {
    unsigned u = __builtin_bit_cast(unsigned, f);
    unsigned r = (u + 0x7fffu + ((u >> 16) & 1u)) >> 16;
    return (unsigned short)r;
}
__device__ __forceinline__ float bf2f(unsigned short u) {
    unsigned x = ((unsigned)u) << 16;
    return __builtin_bit_cast(float, x);
}

#define GLDS16(g, s)                                                        \
    __builtin_amdgcn_global_load_lds(                                       \
        (const __attribute__((address_space(1))) void*)(g),                 \
        (__attribute__((address_space(3))) void*)(s), 16, 0, 0)

// ---------------------------------------------------------------------------
// bf16 MFMA GEMM: C[M,N] = A[M,K] * B[N,K]^T + bias (+res fp32) (+relu)
// A row remap: r -> A + (r/rpbA)*bstrideA + (r%rpbA)*ldA   (conv-as-GEMM)
// Outputs: Cf (fp32) and/or Cb (bf16), ld ldC; cols >= ctcol0 (Ct!=null) go
// TRANSPOSED to Ct[(row>>10)<<20 + (col-ctcol0)*1024 + (row&1023)] (attn V^T).
// Tile 128(M)x64(N), BK=32, 4 waves in 2x2 (each wave 64x32, acc 4x2).
// Grid: (N/64, ceil(M/128)) -> 512+ blocks for N>=1024 => 2+ blocks/CU.
// Double-buffered; K-loop order is ds_read -> GLDS prefetch -> MFMA -> barrier
// so no false vmcnt dependency can stall the ds_reads (R4 regression fix).
// XCD m-slab swizzle for L2 locality.
// ---------------------------------------------------------------------------
__global__ __launch_bounds__(256) void gemm_mfma_k(
    const __hip_bfloat16* __restrict__ A, int rpbA, long long bstrideA, int ldA,
    const __hip_bfloat16* __restrict__ B,
    const float* __restrict__ bias,
    const float* __restrict__ res,
    float* __restrict__ Cf,
    __hip_bfloat16* __restrict__ Cb,
    unsigned short* __restrict__ Ct, int ctcol0,
    int M, int N, int K, int ldC, int relu)
{
    __shared__ __align__(16) __hip_bfloat16 As[2][8][64][8];
    __shared__ __align__(16) __hip_bfloat16 Bs[2][4][64][8];
    const int t  = threadIdx.x;
    const int w  = t >> 6;
    const int l  = t & 63;

    int bx = blockIdx.x, by = blockIdx.y;
    {
        int nbx = gridDim.x;
        int nb  = nbx * gridDim.y;
        if ((nb & 7) == 0) {
            int bid = by * nbx + bx;
            int nid = (bid & 7) * (nb >> 3) + (bid >> 3);
            by = nid / nbx;
            bx = nid - by * nbx;
        }
    }
    const int m0 = by * 128;
    const int n0 = bx * 64;
    const int r16 = l & 15;
    const int qb  = l >> 4;
    const int wm = w >> 1, wn = w & 1;   // wave covers rows 64*wm.., cols 32*wn..

    // staging sources: wave w stages A m-tiles {2w,2w+1}, B n-tile {w}
    const __hip_bfloat16* gA[2];
#pragma unroll
    for (int tt = 0; tt < 2; tt++) {
        int arow = m0 + 16 * (2 * w + tt) + r16;
        gA[tt] = A + (long long)(arow / rpbA) * bstrideA
                   + (long long)(arow % rpbA) * ldA + qb * 8;
    }
    const __hip_bfloat16* gB = B + (long long)(n0 + 16 * w + r16) * K + qb * 8;

    v4f acc[4][2];
#pragma unroll
    for (int i = 0; i < 4; i++)
#pragma unroll
        for (int j = 0; j < 2; j++) acc[i][j] = (v4f){0.f, 0.f, 0.f, 0.f};

    // prologue: stage chunk 0 into buf 0
    GLDS16(gA[0], &As[0][2 * w + 0][0][0]);
    GLDS16(gA[1], &As[0][2 * w + 1][0][0]);
    GLDS16(gB,    &Bs[0][w][0][0]);
    __syncthreads();

    int cur = 0;
    for (int k0 = 32; k0 < K; k0 += 32) {
        // 1) read current fragments (no pending vm ops here -> no stall)
        v8bf af[4], bfr[2];
#pragma unroll
        for (int i = 0; i < 4; i++) af[i]  = *(const v8bf*)(&As[cur][4 * wm + i][l][0]);
#pragma unroll
        for (int j = 0; j < 2; j++) bfr[j] = *(const v8bf*)(&Bs[cur][2 * wn + j][l][0]);
        // 2) prefetch next chunk into the other buffer
        GLDS16(gA[0] + k0, &As[cur ^ 1][2 * w + 0][0][0]);
        GLDS16(gA[1] + k0, &As[cur ^ 1][2 * w + 1][0][0]);
        GLDS16(gB + k0,    &Bs[cur ^ 1][w][0][0]);
        // 3) compute
#pragma unroll
        for (int i = 0; i < 4; i++)
#pragma unroll
            for (int j = 0; j < 2; j++)
                acc[i][j] = __builtin_amdgcn_mfma_f32_16x16x32_bf16(
                    af[i], bfr[j], acc[i][j], 0, 0, 0);
        __syncthreads();
        cur ^= 1;
    }
    {
        v8bf af[4], bfr[2];
#pragma unroll
        for (int i = 0; i < 4; i++) af[i]  = *(const v8bf*)(&As[cur][4 * wm + i][l][0]);
#pragma unroll
        for (int j = 0; j < 2; j++) bfr[j] = *(const v8bf*)(&Bs[cur][2 * wn + j][l][0]);
#pragma unroll
        for (int i = 0; i < 4; i++)
#pragma unroll
            for (int j = 0; j < 2; j++)
                acc[i][j] = __builtin_amdgcn_mfma_f32_16x16x32_bf16(
                    af[i], bfr[j], acc[i][j], 0, 0, 0);
    }

    float bv[2];
#pragma unroll
    for (int j = 0; j < 2; j++) bv[j] = bias[n0 + 32 * wn + 16 * j + r16];
    const int colbase = n0 + 32 * wn + r16;
#pragma unroll
    for (int i = 0; i < 4; i++) {
        int rowb = m0 + 64 * wm + 16 * i + qb * 4;
#pragma unroll
        for (int j = 0; j < 2; j++) {
            int col = colbase + 16 * j;
            float v[4];
#pragma unroll
            for (int r = 0; r < 4; r++) v[r] = acc[i][j][r] + bv[j];
            if (Ct && col >= ctcol0) {
                if (rowb + 3 < M) {
                    ushort4 o;
                    o.x = f2bfu(v[0]); o.y = f2bfu(v[1]);
                    o.z = f2bfu(v[2]); o.w = f2bfu(v[3]);
                    *(ushort4*)(Ct + ((long long)(rowb >> 10) << 20)
                                + (long long)(col - ctcol0) * 1024 + (rowb & 1023)) = o;
                }
            } else {
#pragma unroll
                for (int r = 0; r < 4; r++) {
                    int row = rowb + r;
                    if (row >= M) continue;
                    long long off = (long long)row * ldC + col;
                    float vv = v[r];
                    if (res)  vv += res[off];
                    if (relu) vv = fmaxf(vv, 0.f);
                    if (Cf) Cf[off] = vv;
                    if (Cb) ((unsigned short*)Cb)[off] = f2bfu(vv);
                }
            }
        }
    }
}

// ---------------------------------------------------------------------------
// MFMA softsign attention (unchanged from R3).
// ---------------------------------------------------------------------------
__global__ __launch_bounds__(256) void attn_mfma_k(
    const unsigned short* __restrict__ QKV,
    const unsigned short* __restrict__ Vt,
    unsigned short* __restrict__ O)
{
    __shared__ __align__(16) unsigned short lds[25600];
    const int t = threadIdx.x, w = t >> 6, l = t & 63;
    const int bh = blockIdx.y, b = bh >> 4, h = bh & 15;
    const int s0 = blockIdx.x << 7;
    const int r16 = l & 15, q4 = l >> 4;
    const long long qrow0 = (long long)(b << 10) + s0;
    const int hoff = h << 6;

#pragma unroll
    for (int mi = 0; mi < 2; mi++)
#pragma unroll
        for (int kk = 0; kk < 2; kk++) {
            const unsigned short* g = QKV + (qrow0 + 32 * w + 16 * mi + r16) * 3072
                                      + hoff + 32 * kk + q4 * 8;
            GLDS16(g, &lds[(w * 4 + mi * 2 + kk) * 512]);
        }
    __syncthreads();
    v8bf qf[2][2];
#pragma unroll
    for (int mi = 0; mi < 2; mi++)
#pragma unroll
        for (int kk = 0; kk < 2; kk++)
            qf[mi][kk] = *(const v8bf*)&lds[(w * 4 + mi * 2 + kk) * 512 + l * 8];

    v4f oacc[2][4];
#pragma unroll
    for (int i = 0; i < 2; i++)
#pragma unroll
        for (int j = 0; j < 4; j++) oacc[i][j] = (v4f){0.f, 0.f, 0.f, 0.f};

    for (int t0 = 0; t0 < 1024; t0 += 64) {
#pragma unroll
        for (int rr = 0; rr < 2; rr++) {
            int r = 2 * w + rr, kk = r >> 2, j = r & 3;
            const unsigned short* gk = QKV
                + ((long long)(b << 10) + t0 + 16 * j + r16) * 3072
                + 1024 + hoff + 32 * kk + q4 * 8;
            GLDS16(gk, &lds[8192 + r * 512]);
            const unsigned short* gv = Vt + ((long long)b << 20)
                + (long long)(hoff + 16 * j + r16) * 1024 + t0 + 32 * kk + q4 * 8;
            GLDS16(gv, &lds[12288 + r * 512]);
        }
        __syncthreads();

        v8bf kf[2][4];
#pragma unroll
        for (int kk = 0; kk < 2; kk++)
#pragma unroll
            for (int j = 0; j < 4; j++)
                kf[kk][j] = *(const v8bf*)&lds[8192 + (kk * 4 + j) * 512 + l * 8];
        v4f sc[2][4];
#pragma unroll
        for (int i = 0; i < 2; i++)
#pragma unroll
            for (int j = 0; j < 4; j++) sc[i][j] = (v4f){0.f, 0.f, 0.f, 0.f};
#pragma unroll
        for (int kk = 0; kk < 2; kk++)
#pragma unroll
            for (int mi = 0; mi < 2; mi++)
#pragma unroll
                for (int j = 0; j < 4; j++)
                    sc[mi][j] = __builtin_amdgcn_mfma_f32_16x16x32_bf16(
                        qf[mi][kk], kf[kk][j], sc[mi][j], 0, 0, 0);

#pragma unroll
        for (int mi = 0; mi < 2; mi++)
#pragma unroll
            for (int j = 0; j < 4; j++)
#pragma unroll
                for (int r = 0; r < 4; r++) {
                    float v = sc[mi][j][r] * 0.125f;
                    float p = v * __builtin_amdgcn_rcpf(1.0f + fabsf(v));
                    lds[16384 + (32 * w + 16 * mi + q4 * 4 + r) * 72 + 16 * j + r16] = f2bfu(p);
                }

        v8bf pf[2][2], vf[2][4];
#pragma unroll
        for (int mi = 0; mi < 2; mi++)
#pragma unroll
            for (int kk = 0; kk < 2; kk++)
                pf[mi][kk] = *(const v8bf*)&lds[16384 + (32 * w + 16 * mi + r16) * 72
                                                + 32 * kk + q4 * 8];
#pragma unroll
        for (int kk = 0; kk < 2; kk++)
#pragma unroll
            for (int j = 0; j < 4; j++)
                vf[kk][j] = *(const v8bf*)&lds[12288 + (kk * 4 + j) * 512 + l * 8];
#pragma unroll
        for (int kk = 0; kk < 2; kk++)
#pragma unroll
            for (int mi = 0; mi < 2; mi++)
#pragma unroll
                for (int j = 0; j < 4; j++)
                    oacc[mi][j] = __builtin_amdgcn_mfma_f32_16x16x32_bf16(
                        pf[mi][kk], vf[kk][j], oacc[mi][j], 0, 0, 0);
        __syncthreads();
    }

#pragma unroll
    for (int mi = 0; mi < 2; mi++)
#pragma unroll
        for (int j = 0; j < 4; j++)
#pragma unroll
            for (int r = 0; r < 4; r++)
                lds[(32 * w + 16 * mi + q4 * 4 + r) * 72 + 16 * j + r16] =
                    f2bfu(oacc[mi][j][r]);
    __syncthreads();
    {
        int row = t >> 1, ch = (t & 1) << 5;
#pragma unroll
        for (int i = 0; i < 4; i++) {
            v8us vv = *(const v8us*)&lds[row * 72 + ch + 8 * i];
            *(v8us*)(O + (qrow0 + row) * 1024 + hoff + ch + 8 * i) = vv;
        }
    }
}

// ---------------------------------------------------------------------------
__global__ __launch_bounds__(256) void layernorm_k(
    const float* __restrict__ x, const float* __restrict__ w,
    const float* __restrict__ b, unsigned short* __restrict__ y)
{
    int row = blockIdx.x;
    int t = threadIdx.x;
    float4 v = ((const float4*)(x + ((long long)row << 10)))[t];
    float s = v.x + v.y + v.z + v.w;
#pragma unroll
    for (int o = 32; o; o >>= 1) s += __shfl_down(s, o);
    __shared__ float red[4];
    __shared__ float red2[4];
    int wid = t >> 6, lane = t & 63;
    if (lane == 0) red[wid] = s;
    __syncthreads();
    float mean = (red[0] + red[1] + red[2] + red[3]) * (1.0f / 1024.0f);
    float dx = v.x - mean, dy = v.y - mean, dz = v.z - mean, dw = v.w - mean;
    float sq = dx * dx + dy * dy + dz * dz + dw * dw;
#pragma unroll
    for (int o = 32; o; o >>= 1) sq += __shfl_down(sq, o);
    if (lane == 0) red2[wid] = sq;
    __syncthreads();
    float var = (red2[0] + red2[1] + red2[2] + red2[3]) * (1.0f / 1023.0f);
    float inv = 1.0f / (sqrtf(var) + 1e-6f);
    float4 W  = ((const float4*)w)[t];
    float4 Bv = ((const float4*)b)[t];
    ushort4 o;
    o.x = f2bfu(W.x * (dx * inv) + Bv.x);
    o.y = f2bfu(W.y * (dy * inv) + Bv.y);
    o.z = f2bfu(W.z * (dz * inv) + Bv.z);
    o.w = f2bfu(W.w * (dw * inv) + Bv.w);
    ((ushort4*)(y + ((long long)row << 10)))[t] = o;
}

// ---------------------------------------------------------------------------
__global__ __launch_bounds__(256) void add_pos_k(float* __restrict__ h)
{
    int idx = blockIdx.x * 256 + threadIdx.x;
    int d = idx & 1023;
    int s = (idx >> 10) & 1023;
    int e = d & ~1;
    float div = expf(-9.210340371976184f * (float)e * (1.0f / 1024.0f));
    float arg = (float)s * div;
    float pe = (d & 1) ? cosf(arg) : sinf(arg);
    h[idx] += pe;
}

__global__ __launch_bounds__(256) void convert_k(
    const float* __restrict__ src, unsigned short* __restrict__ dst, int n4)
{
    int i = blockIdx.x * 256 + threadIdx.x;
    if (i >= n4) return;
    float4 v = ((const float4*)src)[i];
    ushort4 o;
    o.x = f2bfu(v.x); o.y = f2bfu(v.y); o.z = f2bfu(v.z); o.w = f2bfu(v.w);
    ((ushort4*)dst)[i] = o;
}

// One launch converts all 6 weight matrices of a layer into the contiguous
// bf16 region starting at wq_b (regions of 256K float4: q,k,v,o,f1lo,f1hi,f2lo,f2hi)
__global__ __launch_bounds__(256) void convert_layer_k(
    const float* __restrict__ q, const float* __restrict__ k,
    const float* __restrict__ v, const float* __restrict__ o,
    const float* __restrict__ f1, const float* __restrict__ f2,
    unsigned short* __restrict__ dst)
{
    int idx = blockIdx.x * 256 + threadIdx.x;
    int region = idx >> 18;
    int r = idx & 0x3FFFF;
    const float* src;
    switch (region) {
        case 0: src = q; break;
        case 1: src = k; break;
        case 2: src = v; break;
        case 3: src = o; break;
        case 4: src = f1; break;
        case 5: src = f1 + 1048576; break;
        case 6: src = f2; break;
        default: src = f2 + 1048576; break;
    }
    float4 vv = ((const float4*)src)[r];
    ushort4 ov;
    ov.x = f2bfu(vv.x); ov.y = f2bfu(vv.y); ov.z = f2bfu(vv.z); ov.w = f2bfu(vv.w);
    ((ushort4*)dst)[(region << 18) + r] = ov;
}

__global__ __launch_bounds__(256) void concat3_k(
    const float* __restrict__ a, const float* __restrict__ b,
    const float* __restrict__ c, float* __restrict__ o)
{
    int i = blockIdx.x * 256 + threadIdx.x;
    o[i] = (i < 1024) ? a[i] : ((i < 2048) ? b[i - 1024] : c[i - 2048]);
}

__global__ __launch_bounds__(256) void reorder_w_k(
    const float* __restrict__ src, unsigned short* __restrict__ dst, int OC, int IC)
{
    int idx = blockIdx.x * 256 + threadIdx.x;
    if (idx >= OC * IC * 3) return;
    int k  = idx % 3;
    int ic = (idx / 3) % IC;
    int oc = idx / (3 * IC);
    dst[(oc * 3 + k) * IC + ic] = f2bfu(src[idx]);
}

__global__ __launch_bounds__(256) void meanpool_k(
    const float* __restrict__ h, float* __restrict__ p)
{
    int g = blockIdx.x * 256 + threadIdx.x;
    int b = g >> 10, d = g & 1023;
    const float* base = h + ((long long)b << 20) + d;
    float s = 0.f;
    for (int i = 0; i < 1024; i++) s += base[(long long)i << 10];
    p[g] = s * (1.0f / 1024.0f);
}

__global__ __launch_bounds__(256) void fc_k(
    const float* __restrict__ p, const float* __restrict__ w,
    const float* __restrict__ fb, float* __restrict__ out)
{
    int b = blockIdx.x, t = threadIdx.x;
    float s = 0.f;
    for (int i = t; i < 1024; i += 256) s += p[(b << 10) + i] * w[i];
#pragma unroll
    for (int o = 32; o; o >>= 1) s += __shfl_down(s, o);
    __shared__ float red[4];
    if ((t & 63) == 0) red[t >> 6] = s;
    __syncthreads();
    if (t == 0) out[b] = red[0] + red[1] + red[2] + red[3] + fb[0];
}

// ---------------------------------------------------------------------------
extern "C" void kernel_launch(void* const* d_in, const int* in_sizes, int n_in,
                              void* d_out, int out_size, void* d_ws, size_t ws_size,
                              hipStream_t stream)
{
    const float* x    = (const float*)d_in[0];
    const float* c1w  = (const float*)d_in[1];
    const float* c1b  = (const float*)d_in[2];
    const float* c2w  = (const float*)d_in[3];
    const float* c2b  = (const float*)d_in[4];
    const float* lnAw = (const float*)d_in[5];
    const float* lnAb = (const float*)d_in[6];
    const float* qw   = (const float*)d_in[7];
    const float* qbi  = (const float*)d_in[8];
    const float* kw   = (const float*)d_in[9];
    const float* kbi  = (const float*)d_in[10];
    const float* vw   = (const float*)d_in[11];
    const float* vbi  = (const float*)d_in[12];
    const float* ow   = (const float*)d_in[13];
    const float* obi  = (const float*)d_in[14];
    const float* lnBw = (const float*)d_in[15];
    const float* lnBb = (const float*)d_in[16];
    const float* f1w  = (const float*)d_in[17];
    const float* f1b  = (const float*)d_in[18];
    const float* f2w  = (const float*)d_in[19];
    const float* f2b  = (const float*)d_in[20];
    const float* fcw  = (const float*)d_in[21];
    const float* fcb  = (const float*)d_in[22];
    float* out = (float*)d_out;

    float* ws = (float*)d_ws;
    typedef __hip_bfloat16 bf;
    typedef unsigned short us;
    float* h    = ws;                          // 4,194,304 f
    us* hn_b    = (us*)(ws + 4194304);         // 4M us
    us* qkv_b   = (us*)(ws + 6291456);         // [4096][3072] us
    us* ff_b    = qkv_b;                       // [4096][2048] us overlay
    us* wq_b    = (us*)(ws + 12582912);        // contiguous: q,k,v,o,f1,f2
    us* wo_b    = (us*)(ws + 14155776);
    us* wf1_b   = (us*)(ws + 14680064);
    us* wf2_b   = (us*)(ws + 15728640);
    us* xb      = (us*)(ws + 16777216);
    us* h1b     = (us*)(ws + 16912896);
    us* w1t_b   = (us*)(ws + 17963520);
    us* w2t_b   = (us*)(ws + 18012672);
    float* pooled = ws + 18799104;             // 4,096 f
    us* Vt      = (us*)(ws + 18803200);        // [4][1024 d][1024 t] us
    float* bqkv = ws + 20900352;               // 3,072 f

    convert_k<<<dim3(257), 256, 0, stream>>>(x, xb, 65792);
    reorder_w_k<<<dim3(384),  256, 0, stream>>>(c1w, w1t_b, 512, 64);
    reorder_w_k<<<dim3(6144), 256, 0, stream>>>(c2w, w2t_b, 1024, 512);

    // conv1: M=4104, N=512, K=192
    gemm_mfma_k<<<dim3(8, 33), 256, 0, stream>>>(
        (const bf*)xb, 1026, 1028LL * 64, 64, (const bf*)w1t_b,
        c1b, nullptr, nullptr, (bf*)h1b, nullptr, 0, 4104, 512, 192, 512, 0);
    // conv2: M=4096, N=1024, K=1536
    gemm_mfma_k<<<dim3(16, 32), 256, 0, stream>>>(
        (const bf*)h1b, 1024, 1026LL * 512, 512, (const bf*)w2t_b,
        c2b, nullptr, h, nullptr, nullptr, 0, 4096, 1024, 1536, 1024, 0);
    add_pos_k<<<dim3(16384), 256, 0, stream>>>(h);

    for (int l = 0; l < 4; l++) {
        long long wo  = (long long)l * 1048576;
        long long wo2 = (long long)l * 2097152;
        convert_layer_k<<<dim3(8192), 256, 0, stream>>>(
            qw + wo, kw + wo, vw + wo, ow + wo, f1w + wo2, f2w + wo2, wq_b);
        concat3_k<<<dim3(12), 256, 0, stream>>>(qbi + l * 1024, kbi + l * 1024,
                                                vbi + l * 1024, bqkv);

        layernorm_k<<<dim3(4096), 256, 0, stream>>>(h, lnAw + l * 1024, lnAb + l * 1024, hn_b);
        // fused QKV: N=3072; cols >=2048 (V) written transposed into Vt
        gemm_mfma_k<<<dim3(48, 32), 256, 0, stream>>>(
            (const bf*)hn_b, 1 << 30, 0, 1024, (const bf*)wq_b,
            bqkv, nullptr, nullptr, (bf*)qkv_b, Vt, 2048, 4096, 3072, 1024, 3072, 0);
        attn_mfma_k<<<dim3(8, 64), 256, 0, stream>>>(qkv_b, Vt, hn_b);
        gemm_mfma_k<<<dim3(16, 32), 256, 0, stream>>>(
            (const bf*)hn_b, 1 << 30, 0, 1024, (const bf*)wo_b,
            obi + l * 1024, h, h, nullptr, nullptr, 0, 4096, 1024, 1024, 1024, 0);
        layernorm_k<<<dim3(4096), 256, 0, stream>>>(h, lnBw + l * 1024, lnBb + l * 1024, hn_b);
        gemm_mfma_k<<<dim3(32, 32), 256, 0, stream>>>(
            (const bf*)hn_b, 1 << 30, 0, 1024, (const bf*)wf1_b,
            f1b + l * 2048, nullptr, nullptr, (bf*)ff_b, nullptr, 0, 4096, 2048, 1024, 2048, 1);
        gemm_mfma_k<<<dim3(16, 32), 256, 0, stream>>>(
            (const bf*)ff_b, 1 << 30, 0, 2048, (const bf*)wf2_b,
            f2b + l * 1024, h, h, nullptr, nullptr, 0, 4096, 1024, 2048, 1024, 0);
    }

    meanpool_k<<<dim3(16), 256, 0, stream>>>(h, pooled);
    fc_k<<<dim3(4), 256, 0, stream>>>(pooled, fcw, fcb, out);
}